// Round 1
// 3062.914 us; speedup vs baseline: 1.2202x; 1.2202x over previous
//
#include <hip/hip_runtime.h>
#include <hip/hip_bf16.h>

// ============================================================================
// Net_72662256713812 — round 4: kill the f32 embed GEMM bottleneck.
//  - rocprof: old f32 gemm_k (emb_w2) = 159us @ 5.6% occupancy, 10% VALU.
//  - routing identity: embed@router == h@(emb_w2@router). Precompute
//    R2[l]=emb_w2@router_l in f64 (adds ~0 error) -> route straight from h.
//  - embedF only feeds embed_out (bf16-tolerant) -> compute via MFMA.
//  - all-8-layers routing in ONE pass over h; all-8 bucket sorts in ONE
//    8-block dispatch (was 8 serial single-block launches).
//  - Q/K/V projections fused into one 384-block MFMA dispatch (was 3x128).
// ============================================================================

typedef __bf16 bf16x8 __attribute__((ext_vector_type(8)));
typedef float f32x4 __attribute__((ext_vector_type(4)));

#define B_ 4
#define T_ 512
#define IN_ 80
#define OUT_ 4096
#define D_ 512
#define HID_ 1024
#define E_ 4
#define H_ 8
#define DH_ 64
#define M_ 64
#define BT_ (B_ * T_)        // 2048
#define TKV_ (T_ + M_)       // 576

// ---------------------------------------------------------------- embed w1 (f32, K=80)
// h = relu(x @ emb_w1 + b1). 64x64 tile, 4x4 micro, single LDS stage (full K).
__global__ __launch_bounds__(256) void gemm80_k(
    const float* __restrict__ A,    // [BT_][80]
    const float* __restrict__ Bw,   // [80][1024]
    const float* __restrict__ bias, // [1024]
    float* __restrict__ C)          // [BT_][1024]
{
    __shared__ float As[80][68];   // [k][m]
    __shared__ float Bs[80][68];   // [k][n]
    int m0 = blockIdx.y * 64, n0 = blockIdx.x * 64;
    int tid = threadIdx.x;
    // stage A: 64 rows x 20 float4
#pragma unroll
    for (int i = 0; i < 5; i++) {
        int idx = tid + 256 * i;          // 0..1279
        int m = idx / 20, c = idx % 20;
        float4 f = *(const float4*)&A[(size_t)(m0 + m) * 80 + c * 4];
        As[c * 4 + 0][m] = f.x; As[c * 4 + 1][m] = f.y;
        As[c * 4 + 2][m] = f.z; As[c * 4 + 3][m] = f.w;
    }
    // stage B: 80 k-rows x 16 float4
#pragma unroll
    for (int i = 0; i < 5; i++) {
        int idx = tid + 256 * i;
        int k = idx / 16, c = idx % 16;
        float4 f = *(const float4*)&Bw[(size_t)k * 1024 + n0 + c * 4];
        *(float4*)&Bs[k][c * 4] = f;
    }
    __syncthreads();
    int tx = tid & 15, ty = tid >> 4;
    float acc[4][4];
#pragma unroll
    for (int j = 0; j < 4; j++)
#pragma unroll
        for (int i = 0; i < 4; i++) acc[j][i] = 0.f;
#pragma unroll 8
    for (int k = 0; k < 80; k++) {
        float4 a = *(const float4*)&As[k][ty * 4];
        float4 b = *(const float4*)&Bs[k][tx * 4];
        float av[4] = {a.x, a.y, a.z, a.w};
        float bv[4] = {b.x, b.y, b.z, b.w};
#pragma unroll
        for (int j = 0; j < 4; j++)
#pragma unroll
            for (int i = 0; i < 4; i++) acc[j][i] += av[j] * bv[i];
    }
#pragma unroll
    for (int j = 0; j < 4; j++) {
        size_t row = (size_t)(m0 + ty * 4 + j);
        float4 o;
        o.x = fmaxf(acc[j][0] + bias[n0 + tx * 4 + 0], 0.f);
        o.y = fmaxf(acc[j][1] + bias[n0 + tx * 4 + 1], 0.f);
        o.z = fmaxf(acc[j][2] + bias[n0 + tx * 4 + 2], 0.f);
        o.w = fmaxf(acc[j][3] + bias[n0 + tx * 4 + 3], 0.f);
        *(float4*)&C[row * 1024 + n0 + tx * 4] = o;
    }
}

// ---------------------------------------------------------------- R2 = emb_w2 @ router_l (f64 accum)
__global__ void wr2_k(const float* __restrict__ w2,   // [1024][512]
                      const float* __restrict__ r0,   // [512][4]
                      const float* __restrict__ rl,   // [7][512][4]
                      float* __restrict__ R2)         // [8][1024][4]
{
    int wv = threadIdx.x >> 6, lane = threadIdx.x & 63;
    int h = blockIdx.x * 4 + wv;
    const float* wrow = w2 + (size_t)h * 512;
    float w[8];
#pragma unroll
    for (int i = 0; i < 8; i++) w[i] = wrow[lane + 64 * i];
    for (int l = 0; l < 8; l++) {
        const float* rp = (l == 0) ? r0 : rl + (size_t)(l - 1) * 2048;
        double a0 = 0, a1 = 0, a2 = 0, a3 = 0;
#pragma unroll
        for (int i = 0; i < 8; i++) {
            int d = lane + 64 * i;
            float4 r = *(const float4*)&rp[d * 4];
            a0 += (double)w[i] * (double)r.x;
            a1 += (double)w[i] * (double)r.y;
            a2 += (double)w[i] * (double)r.z;
            a3 += (double)w[i] * (double)r.w;
        }
        for (int off = 32; off; off >>= 1) {
            a0 += __shfl_xor(a0, off); a1 += __shfl_xor(a1, off);
            a2 += __shfl_xor(a2, off); a3 += __shfl_xor(a3, off);
        }
        if (lane == 0) {
            float4 o = make_float4((float)a0, (float)a1, (float)a2, (float)a3);
            *(float4*)&R2[((size_t)l * 1024 + h) * 4] = o;
        }
    }
}

// ---------------------------------------------------------------- all-layers routing from h
__global__ __launch_bounds__(256) void routerall_k(
    const float* __restrict__ h,    // [BT_][1024]
    const float* __restrict__ R2,   // [8][1024][4]
    const int* __restrict__ seq_len,
    int* __restrict__ eid,          // [8][BT_]
    float* __restrict__ gatev,      // [8][BT_]
    float* __restrict__ imp)        // [8][4]
{
    int wv = threadIdx.x >> 6, lane = threadIdx.x & 63;
    int tok = blockIdx.x * 4 + wv;
    const float* hr = h + (size_t)tok * 1024;
    float acc[8][4];
#pragma unroll
    for (int l = 0; l < 8; l++)
#pragma unroll
        for (int e = 0; e < 4; e++) acc[l][e] = 0.f;
    for (int i = 0; i < 16; i++) {
        int d = lane + 64 * i;
        float hv = hr[d];
#pragma unroll
        for (int l = 0; l < 8; l++) {
            float4 r = *(const float4*)&R2[((size_t)l * 1024 + d) * 4];
            acc[l][0] += hv * r.x; acc[l][1] += hv * r.y;
            acc[l][2] += hv * r.z; acc[l][3] += hv * r.w;
        }
    }
    for (int off = 32; off; off >>= 1) {
#pragma unroll
        for (int l = 0; l < 8; l++)
#pragma unroll
            for (int e = 0; e < 4; e++) acc[l][e] += __shfl_xor(acc[l][e], off);
    }
    if (lane == 0) {
        int b = tok >> 9, t = tok & 511;
        bool valid = t < seq_len[b];
        for (int l = 0; l < 8; l++) {
            float lg[4] = {acc[l][0], acc[l][1], acc[l][2], acc[l][3]};
            float mx = fmaxf(fmaxf(lg[0], lg[1]), fmaxf(lg[2], lg[3]));
            float g[4], s = 0.f;
            for (int e = 0; e < 4; e++) { g[e] = expf(lg[e] - mx); s += g[e]; }
            float inv = 1.f / s;
            int am = 0; float bv = g[0];
            for (int e = 1; e < 4; e++) if (g[e] > bv) { bv = g[e]; am = e; }
            eid[l * BT_ + tok] = am;
            gatev[l * BT_ + tok] = bv * inv;
            if (valid)
                for (int e = 0; e < 4; e++) atomicAdd(&imp[l * 4 + e], g[e] * inv);
        }
    }
}

// ---------------------------------------------------------------- MFMA GEMM
#define MBM 128
#define MBN 64
#define MBK 32
#define LDAS 40   // bf16 elems per LDS row (32 + 8 pad; 80B = 16B-multiple)

__device__ __forceinline__ unsigned pk2(float a, float b) {
    unsigned short ua = __builtin_bit_cast(unsigned short, (__bf16)a);
    unsigned short ub = __builtin_bit_cast(unsigned short, (__bf16)b);
    return (unsigned)ua | ((unsigned)ub << 16);
}

template<bool EXPERT, bool GATHER, bool SCATTER, bool RELU, bool BIAS>
__global__ __launch_bounds__(256) void mgemm_k(
    const float* __restrict__ A, int lda,
    const float* __restrict__ Bw,         // [K,N] row-major (+ e*K*N if EXPERT)
    const float* __restrict__ bias,
    float* __restrict__ C, int ldc, int M, int N, int K,
    const int* __restrict__ seg, const int* __restrict__ sorted,
    const float* __restrict__ scale, int remM)
{
    __shared__ __align__(16) __bf16 As[MBM * LDAS];
    __shared__ __align__(16) __bf16 Bs[MBN * LDAS];

    int e = EXPERT ? blockIdx.z : 0;
    int row0 = 0, cnt = M;
    if (EXPERT) { row0 = seg[e]; cnt = seg[e + 1] - row0; }
    int m0 = blockIdx.y * MBM;
    if (m0 >= cnt) return;
    int n0 = blockIdx.x * MBN;
    const float* Bp = Bw + (EXPERT ? (size_t)e * K * N : 0);

    int tid = threadIdx.x;
    int arow = tid >> 1, ahalf = tid & 1;
    const float* aptr;
    {
        int m = m0 + arow;
        int srow;
        if (EXPERT) { int mm = (m < cnt) ? m : (cnt - 1); int ci = row0 + mm;
                      srow = GATHER ? sorted[ci] : ci; }
        else srow = m;
        aptr = A + (size_t)srow * lda + ahalf * 16;
    }
    int asw = (arow >> 3) & 3;
    int bn = tid & 63, bkc = tid >> 6;
    int bcs = bkc ^ ((bn >> 3) & 3);

    int lane = tid & 63, wid = tid >> 6;
    int wm = wid & 1, wn = wid >> 1;
    int l15 = lane & 15, quad = lane >> 4;

    int aoff[4], boff[2];
#pragma unroll
    for (int mt = 0; mt < 4; mt++) {
        int m = wm * 64 + mt * 16 + l15;
        aoff[mt] = m * LDAS + (quad ^ ((m >> 3) & 3)) * 8;
    }
#pragma unroll
    for (int nt = 0; nt < 2; nt++) {
        int n = wn * 32 + nt * 16 + l15;
        boff[nt] = n * LDAS + (quad ^ ((n >> 3) & 3)) * 8;
    }

    f32x4 acc[4][2];
#pragma unroll
    for (int mt = 0; mt < 4; mt++)
#pragma unroll
        for (int nt = 0; nt < 2; nt++)
#pragma unroll
            for (int r = 0; r < 4; r++) acc[mt][nt][r] = 0.f;

    for (int k0 = 0; k0 < K; k0 += MBK) {
#pragma unroll
        for (int cc = 0; cc < 2; cc++) {
            int kbase = k0 + ahalf * 16 + cc * 8;
            float4 f0, f1;
            if (kbase < K) {
                f0 = *(const float4*)(aptr + k0 + cc * 8);
                f1 = *(const float4*)(aptr + k0 + cc * 8 + 4);
            } else {
                f0 = make_float4(0.f, 0.f, 0.f, 0.f); f1 = f0;
            }
            uint4 pk = make_uint4(pk2(f0.x, f0.y), pk2(f0.z, f0.w),
                                  pk2(f1.x, f1.y), pk2(f1.z, f1.w));
            int cs = (ahalf * 2 + cc) ^ asw;
            *(uint4*)&As[arow * LDAS + cs * 8] = pk;
        }
        {
            float f[8];
            int kk = k0 + bkc * 8;
#pragma unroll
            for (int i = 0; i < 8; i++) {
                int k = kk + i;
                f[i] = (k < K) ? Bp[(size_t)k * N + n0 + bn] : 0.f;
            }
            uint4 pk = make_uint4(pk2(f[0], f[1]), pk2(f[2], f[3]),
                                  pk2(f[4], f[5]), pk2(f[6], f[7]));
            *(uint4*)&Bs[bn * LDAS + bcs * 8] = pk;
        }
        __syncthreads();
        bf16x8 af[4], bfm[2];
#pragma unroll
        for (int mt = 0; mt < 4; mt++) af[mt] = *(const bf16x8*)&As[aoff[mt]];
#pragma unroll
        for (int nt = 0; nt < 2; nt++) bfm[nt] = *(const bf16x8*)&Bs[boff[nt]];
#pragma unroll
        for (int mt = 0; mt < 4; mt++)
#pragma unroll
            for (int nt = 0; nt < 2; nt++)
                acc[mt][nt] = __builtin_amdgcn_mfma_f32_16x16x32_bf16(
                    af[mt], bfm[nt], acc[mt][nt], 0, 0, 0);
        __syncthreads();
    }

#pragma unroll
    for (int mt = 0; mt < 4; mt++) {
#pragma unroll
        for (int r = 0; r < 4; r++) {
            int mi = wm * 64 + mt * 16 + quad * 4 + r;
            int m = m0 + mi;
            if (EXPERT && m >= cnt) continue;
            size_t crow; float sc = 1.f;
            if (SCATTER) { int tok = sorted[row0 + m]; crow = (size_t)tok; sc = scale[tok]; }
            else if (EXPERT) crow = (size_t)(row0 + m);
            else { crow = (size_t)m; if (remM) crow = (size_t)m + (size_t)(m >> 9) * remM; }
#pragma unroll
            for (int nt = 0; nt < 2; nt++) {
                int col = n0 + wn * 32 + nt * 16 + l15;
                float v = acc[mt][nt][r];
                if (BIAS) v += bias[(EXPERT ? (size_t)e * N : 0) + col];
                if (RELU) v = fmaxf(v, 0.f);
                if (SCATTER) v *= sc;
                C[crow * (size_t)ldc + col] = v;
            }
        }
    }
}

// ---------------------------------------------------------------- fused QKV MFMA GEMM
// [Q|K|V] = curB @ [wq|wk|wv]; N=1536 -> 24x16 = 384 blocks (3x the parallelism
// of the separate 128-block projections, single A read).
__global__ __launch_bounds__(256) void qkv_k(
    const float* __restrict__ A,          // [BT_][512]
    const float* __restrict__ wq, const float* __restrict__ wk,
    const float* __restrict__ wv,
    float* __restrict__ qo, float* __restrict__ ko, float* __restrict__ vo)
{
    __shared__ __align__(16) __bf16 As[MBM * LDAS];
    __shared__ __align__(16) __bf16 Bs[MBN * LDAS];

    int n0g = blockIdx.x * MBN;
    int which = n0g >> 9;
    int n0 = n0g & 511;
    const float* Bp = (which == 0) ? wq : (which == 1) ? wk : wv;
    float* Cp = (which == 0) ? qo : (which == 1) ? ko : vo;
    int m0 = blockIdx.y * MBM;

    int tid = threadIdx.x;
    int arow = tid >> 1, ahalf = tid & 1;
    const float* aptr = A + (size_t)(m0 + arow) * D_ + ahalf * 16;
    int asw = (arow >> 3) & 3;
    int bn = tid & 63, bkc = tid >> 6;
    int bcs = bkc ^ ((bn >> 3) & 3);

    int lane = tid & 63, wid = tid >> 6;
    int wm = wid & 1, wn = wid >> 1;
    int l15 = lane & 15, quad = lane >> 4;

    int aoff[4], boff[2];
#pragma unroll
    for (int mt = 0; mt < 4; mt++) {
        int m = wm * 64 + mt * 16 + l15;
        aoff[mt] = m * LDAS + (quad ^ ((m >> 3) & 3)) * 8;
    }
#pragma unroll
    for (int nt = 0; nt < 2; nt++) {
        int n = wn * 32 + nt * 16 + l15;
        boff[nt] = n * LDAS + (quad ^ ((n >> 3) & 3)) * 8;
    }

    f32x4 acc[4][2];
#pragma unroll
    for (int mt = 0; mt < 4; mt++)
#pragma unroll
        for (int nt = 0; nt < 2; nt++)
#pragma unroll
            for (int r = 0; r < 4; r++) acc[mt][nt][r] = 0.f;

    for (int k0 = 0; k0 < D_; k0 += MBK) {
#pragma unroll
        for (int cc = 0; cc < 2; cc++) {
            float4 f0 = *(const float4*)(aptr + k0 + cc * 8);
            float4 f1 = *(const float4*)(aptr + k0 + cc * 8 + 4);
            uint4 pk = make_uint4(pk2(f0.x, f0.y), pk2(f0.z, f0.w),
                                  pk2(f1.x, f1.y), pk2(f1.z, f1.w));
            int cs = (ahalf * 2 + cc) ^ asw;
            *(uint4*)&As[arow * LDAS + cs * 8] = pk;
        }
        {
            float f[8];
            int kk = k0 + bkc * 8;
#pragma unroll
            for (int i = 0; i < 8; i++)
                f[i] = Bp[(size_t)(kk + i) * D_ + n0 + bn];
            uint4 pk = make_uint4(pk2(f[0], f[1]), pk2(f[2], f[3]),
                                  pk2(f[4], f[5]), pk2(f[6], f[7]));
            *(uint4*)&Bs[bn * LDAS + bcs * 8] = pk;
        }
        __syncthreads();
        bf16x8 af[4], bfm[2];
#pragma unroll
        for (int mt = 0; mt < 4; mt++) af[mt] = *(const bf16x8*)&As[aoff[mt]];
#pragma unroll
        for (int nt = 0; nt < 2; nt++) bfm[nt] = *(const bf16x8*)&Bs[boff[nt]];
#pragma unroll
        for (int mt = 0; mt < 4; mt++)
#pragma unroll
            for (int nt = 0; nt < 2; nt++)
                acc[mt][nt] = __builtin_amdgcn_mfma_f32_16x16x32_bf16(
                    af[mt], bfm[nt], acc[mt][nt], 0, 0, 0);
        __syncthreads();
    }

#pragma unroll
    for (int mt = 0; mt < 4; mt++) {
#pragma unroll
        for (int r = 0; r < 4; r++) {
            int mi = wm * 64 + mt * 16 + quad * 4 + r;
            int m = m0 + mi;
            size_t crow = which ? (size_t)(m + (m >> 9) * M_) : (size_t)m;
#pragma unroll
            for (int nt = 0; nt < 2; nt++) {
                int col = n0 + wn * 32 + nt * 16 + l15;
                Cp[crow * (size_t)D_ + col] = acc[mt][nt][r];
            }
        }
    }
}

// ---------------------------------------------------------------- small ops
__global__ void zero_k(float* p, int n) {
    int i = blockIdx.x * 256 + threadIdx.x;
    if (i < n) p[i] = 0.f;
}

__global__ void bucketall_k(const int* __restrict__ eidA, int* __restrict__ sortedA,
                            int* __restrict__ segA)
{
    __shared__ int cnt[E_]; __shared__ int cur[E_];
    int l = blockIdx.x;
    const int* eid = eidA + l * BT_;
    int* sorted = sortedA + l * BT_;
    int* seg = segA + l * 8;
    int tid = threadIdx.x;
    if (tid < E_) cnt[tid] = 0;
    __syncthreads();
    for (int t = tid; t < BT_; t += 256) atomicAdd(&cnt[eid[t]], 1);
    __syncthreads();
    if (tid == 0) {
        int o = 0;
        for (int e = 0; e < E_; e++) { seg[e] = o; cur[e] = o; o += cnt[e]; }
        seg[E_] = o;
    }
    __syncthreads();
    for (int t = tid; t < BT_; t += 256) {
        int pos = atomicAdd(&cur[eid[t]], 1);
        sorted[pos] = t;
    }
}

__global__ void fsmn_k(const float* __restrict__ p, const float* __restrict__ fb,
                       const float* __restrict__ fa, float* __restrict__ cur, int skip)
{
    int idx = blockIdx.x * 256 + threadIdx.x;
    int d = idx & 511;
    int t = (idx >> 9) & 511;
    float m = p[idx];
#pragma unroll
    for (int k = 0; k < 4; k++) {
        int tt = t - 2 * (k + 1);
        if (tt >= 0) m += fb[k * D_ + d] * p[idx - D_ * 2 * (k + 1)];
    }
    if (t + 1 < T_) m += fa[d] * p[idx + D_];
    if (skip) m += cur[idx];
    cur[idx] = m;
}

__global__ void addpe_k(float* __restrict__ cur) {
    int idx = blockIdx.x * 256 + threadIdx.x;
    int d = idx & 511, t = (idx >> 9) & 511;
    float div = expf((float)(d & ~1) * (-9.210340371976184f / (float)D_));
    float ang = (float)t * div;
    cur[idx] += (d & 1) ? cosf(ang) : sinf(ang);
}

__global__ void fillmem_k(const float* __restrict__ mk, const float* __restrict__ mv,
                          float* __restrict__ kbuf, float* __restrict__ vbuf)
{
    int idx = blockIdx.x * 256 + threadIdx.x;
    int d = idx & 511, m = (idx >> 9) & 63, b = idx >> 15;
    size_t row = (size_t)b * TKV_ + T_ + m;
    kbuf[row * D_ + d] = mk[m * D_ + d];
    vbuf[row * D_ + d] = mv[m * D_ + d];
}

// attention: one block = (b, h, 16 q rows); 4 rows per wave
#define QR 16
__global__ __launch_bounds__(256) void attn_k(
    const float* __restrict__ q, const float* __restrict__ kbuf,
    const float* __restrict__ vbuf, const int* __restrict__ seq_len,
    float* __restrict__ attno)
{
    __shared__ float kv[64 * 69];
    __shared__ float qs[QR][64];
    __shared__ float sc[QR][TKV_];
    int b = blockIdx.z, h = blockIdx.y, t0 = blockIdx.x * QR;
    int tid = threadIdx.x, w = tid >> 6, lane = tid & 63;
    int r0 = w * 4;
#pragma unroll
    for (int i = 0; i < 4; i++) {
        int idx = tid + 256 * i;
        int r = idx >> 6, d = idx & 63;
        qs[r][d] = q[((size_t)(b * T_) + t0 + r) * D_ + h * DH_ + d] * 0.125f;
    }
    int sl = seq_len[b];
    for (int s0 = 0; s0 < TKV_; s0 += 64) {
        __syncthreads();
#pragma unroll
        for (int i = 0; i < 16; i++) {
            int idx = tid + 256 * i;
            int key = idx >> 6, d = idx & 63;
            kv[d * 69 + key] = kbuf[((size_t)b * TKV_ + s0 + key) * D_ + h * DH_ + d];
        }
        __syncthreads();
        float a0 = 0, a1 = 0, a2 = 0, a3 = 0;
#pragma unroll 4
        for (int d = 0; d < 64; d++) {
            float kvv = kv[d * 69 + lane];
            a0 += qs[r0 + 0][d] * kvv;
            a1 += qs[r0 + 1][d] * kvv;
            a2 += qs[r0 + 2][d] * kvv;
            a3 += qs[r0 + 3][d] * kvv;
        }
        int sa = s0 + lane;
        bool ok = (sa >= T_ || sa < sl);
        sc[r0 + 0][sa] = ok ? a0 : -1e9f;
        sc[r0 + 1][sa] = ok ? a1 : -1e9f;
        sc[r0 + 2][sa] = ok ? a2 : -1e9f;
        sc[r0 + 3][sa] = ok ? a3 : -1e9f;
    }
    float inv[4];
#pragma unroll
    for (int r = 0; r < 4; r++) {
        float mx = -1e30f;
        for (int s = lane; s < TKV_; s += 64) mx = fmaxf(mx, sc[r0 + r][s]);
        for (int off = 32; off; off >>= 1) mx = fmaxf(mx, __shfl_xor(mx, off));
        float sum = 0.f;
        for (int s = lane; s < TKV_; s += 64) {
            float e2 = expf(sc[r0 + r][s] - mx); sc[r0 + r][s] = e2; sum += e2;
        }
        for (int off = 32; off; off >>= 1) sum += __shfl_xor(sum, off);
        inv[r] = 1.f / sum;
    }
    float o0 = 0, o1 = 0, o2 = 0, o3 = 0;
    for (int s0 = 0; s0 < TKV_; s0 += 64) {
        __syncthreads();
#pragma unroll
        for (int i = 0; i < 16; i++) {
            int idx = tid + 256 * i;
            int key = idx >> 6, d = idx & 63;
            kv[key * 69 + d] = vbuf[((size_t)b * TKV_ + s0 + key) * D_ + h * DH_ + d];
        }
        __syncthreads();
#pragma unroll 4
        for (int j = 0; j < 64; j++) {
            float vv = kv[j * 69 + lane];
            o0 += sc[r0 + 0][s0 + j] * vv;
            o1 += sc[r0 + 1][s0 + j] * vv;
            o2 += sc[r0 + 2][s0 + j] * vv;
            o3 += sc[r0 + 3][s0 + j] * vv;
        }
    }
    size_t base = ((size_t)(b * T_) + t0 + r0) * D_ + h * DH_ + lane;
    attno[base + 0 * D_] = o0 * inv[0];
    attno[base + 1 * D_] = o1 * inv[1];
    attno[base + 2 * D_] = o2 * inv[2];
    attno[base + 3 * D_] = o3 * inv[3];
}

__global__ void ln_k(const float* __restrict__ o, const float* __restrict__ g,
                     const float* __restrict__ bb, float* __restrict__ cur)
{
    int w = threadIdx.x >> 6, lane = threadIdx.x & 63;
    size_t row = (size_t)(blockIdx.x * 4 + w);
    float v[8]; float s = 0.f;
#pragma unroll
    for (int i = 0; i < 8; i++) {
        int d = lane + 64 * i;
        v[i] = cur[row * D_ + d] + o[row * D_ + d];
        s += v[i];
    }
    for (int off = 32; off; off >>= 1) s += __shfl_xor(s, off);
    float mu = s * (1.f / D_);
    float vs = 0.f;
#pragma unroll
    for (int i = 0; i < 8; i++) { float dd = v[i] - mu; vs += dd * dd; }
    for (int off = 32; off; off >>= 1) vs += __shfl_xor(vs, off);
    float rstd = rsqrtf(vs * (1.f / D_) + 1e-5f);
#pragma unroll
    for (int i = 0; i < 8; i++) {
        int d = lane + 64 * i;
        cur[row * D_ + d] = (v[i] - mu) * rstd * g[d] + bb[d];
    }
}

__global__ void aux_k(const float* __restrict__ imp, float* __restrict__ outp) {
    if (threadIdx.x == 0) {
        float total = 0.f;
        for (int l = 0; l < 8; l++) {
            const float* ip = imp + l * 4;
            float m = (ip[0] + ip[1] + ip[2] + ip[3]) * 0.25f;
            float var = 0.f;
            for (int e = 0; e < 4; e++) { float d = ip[e] - m; var += d * d; }
            var *= 0.25f;
            total += var / (m * m + 1e-9f);
        }
        *outp = total;
    }
}

// ============================================================================
extern "C" void kernel_launch(void* const* d_in, const int* in_sizes, int n_in,
                              void* d_out, int out_size, void* d_ws, size_t ws_size,
                              hipStream_t stream)
{
    (void)in_sizes; (void)n_in; (void)out_size; (void)ws_size;
    const float* x        = (const float*)d_in[0];
    const int*   seqlen   = (const int*)d_in[1];
    const float* emb_w1   = (const float*)d_in[2];
    const float* emb_b1   = (const float*)d_in[3];
    const float* emb_w2   = (const float*)d_in[4];
    const float* emb_wo   = (const float*)d_in[5];
    const float* f0_w1    = (const float*)d_in[6];
    const float* f0_b1    = (const float*)d_in[7];
    const float* f0_w2    = (const float*)d_in[8];
    const float* f0_router= (const float*)d_in[9];
    const float* f0_fb    = (const float*)d_in[10];
    const float* f0_fa    = (const float*)d_in[11];
    const float* f_w1     = (const float*)d_in[12];
    const float* f_b1     = (const float*)d_in[13];
    const float* f_w2     = (const float*)d_in[14];
    const float* f_router = (const float*)d_in[15];
    const float* f_fb     = (const float*)d_in[16];
    const float* f_fa     = (const float*)d_in[17];
    const float* attn_wq  = (const float*)d_in[18];
    const float* attn_wk  = (const float*)d_in[19];
    const float* attn_wv  = (const float*)d_in[20];
    const float* attn_wo  = (const float*)d_in[21];
    const float* attn_mk  = (const float*)d_in[22];
    const float* attn_mv  = (const float*)d_in[23];
    const float* ln_g     = (const float*)d_in[24];
    const float* ln_b     = (const float*)d_in[25];
    const float* out_w    = (const float*)d_in[26];
    const float* out_b    = (const float*)d_in[27];

    float* out0 = (float*)d_out;
    float* out1 = out0 + (size_t)BT_ * OUT_;
    float* out2 = out1 + (size_t)BT_ * OUT_;

    float* fws = (float*)d_ws;
    size_t o = 0;
    float* embedF = fws + o; o += (size_t)BT_ * D_;
    float* curB   = fws + o; o += (size_t)BT_ * D_;
    float* hbuf   = fws + o; o += (size_t)BT_ * HID_;
    float* pbuf   = fws + o; o += (size_t)BT_ * D_;
    float* kbuf   = fws + o; o += (size_t)B_ * TKV_ * D_;
    float* vbuf   = fws + o; o += (size_t)B_ * TKV_ * D_;
    float* gatev  = fws + o; o += (size_t)8 * BT_;
    float* impA   = fws + o; o += 32;
    float* R2     = fws + o; o += (size_t)8 * 1024 * 4;
    int* eid     = (int*)(fws + o); o += (size_t)8 * BT_;
    int* sortedA = (int*)(fws + o); o += (size_t)8 * BT_;
    int* segA    = (int*)(fws + o); o += 64;
    float* qbuf  = pbuf;
    float* attno = hbuf;
    float* tmpo  = hbuf + (size_t)BT_ * D_;

    zero_k<<<1, 64, 0, stream>>>(impA, 32);

    // h = relu(x@emb_w1+b1) — exact f32 (feeds routing), fast K=80 kernel
    gemm80_k<<<dim3(HID_ / 64, BT_ / 64, 1), 256, 0, stream>>>(x, emb_w1, emb_b1, hbuf);
    // R2[l] = emb_w2 @ router_l in f64 — routing reassociation adds ~0 error
    wr2_k<<<256, 256, 0, stream>>>(emb_w2, f0_router, f_router, R2);
    // all 8 layers' routing decisions in one pass over h
    routerall_k<<<BT_ / 4, 256, 0, stream>>>(hbuf, R2, seqlen, eid, gatev, impA);
    // all 8 bucket sorts, one dispatch
    bucketall_k<<<8, 256, 0, stream>>>(eid, sortedA, segA);
    // embedF only feeds embed_out now -> bf16 MFMA is fine
    mgemm_k<false,false,false,false,false><<<dim3(D_/MBN, BT_/MBM, 1), 256, 0, stream>>>(
        hbuf, HID_, emb_w2, nullptr, embedF, D_, BT_, D_, HID_,
        nullptr, nullptr, nullptr, 0);
    mgemm_k<false,false,false,false,false><<<dim3(OUT_/MBN, BT_/MBM, 1), 256, 0, stream>>>(
        embedF, D_, emb_wo, nullptr, out1, OUT_, BT_, OUT_, D_,
        nullptr, nullptr, nullptr, 0);

    for (int l = 0; l < 8; l++) {
        const float* w1  = (l == 0) ? f0_w1 : f_w1 + (size_t)(l-1) * E_ * D_ * HID_;
        const float* b1p = (l == 0) ? f0_b1 : f_b1 + (size_t)(l-1) * E_ * HID_;
        const float* w2  = (l == 0) ? f0_w2 : f_w2 + (size_t)(l-1) * E_ * HID_ * D_;
        const float* fbp = (l == 0) ? f0_fb : f_fb + (size_t)(l-1) * 4 * D_;
        const float* fap = (l == 0) ? f0_fa : f_fa + (size_t)(l-1) * 1 * D_;
        int Kl = (l == 0) ? IN_ : D_;
        const float* Ain = (l == 0) ? x : curB;
        const int* seg = segA + l * 8;
        const int* sorted = sortedA + l * BT_;

        mgemm_k<true,true,false,true,true><<<dim3(HID_/MBN, BT_/MBM, E_), 256, 0, stream>>>(
            Ain, Kl, w1, b1p, hbuf, HID_, BT_, HID_, Kl, seg, sorted, nullptr, 0);
        mgemm_k<true,false,true,false,false><<<dim3(D_/MBN, BT_/MBM, E_), 256, 0, stream>>>(
            hbuf, HID_, w2, nullptr, pbuf, D_, BT_, D_, HID_, seg, sorted,
            gatev + l * BT_, 0);
        fsmn_k<<<BT_*D_/256, 256, 0, stream>>>(pbuf, fbp, fap, curB, (l > 0) ? 1 : 0);

        if (l == 3) addpe_k<<<BT_*D_/256, 256, 0, stream>>>(curB);

        if (l == 3 || l == 7) {
            int ab = (l == 3) ? 0 : 1;
            const float* wq = attn_wq + (size_t)ab * D_ * D_;
            const float* wk = attn_wk + (size_t)ab * D_ * D_;
            const float* wv = attn_wv + (size_t)ab * D_ * D_;
            const float* wo = attn_wo + (size_t)ab * D_ * D_;
            const float* mk = attn_mk + (size_t)ab * M_ * D_;
            const float* mv = attn_mv + (size_t)ab * M_ * D_;
            const float* g  = ln_g + (size_t)ab * D_;
            const float* bb = ln_b + (size_t)ab * D_;

            qkv_k<<<dim3(3 * D_ / MBN, BT_ / MBM, 1), 256, 0, stream>>>(
                curB, wq, wk, wv, qbuf, kbuf, vbuf);
            fillmem_k<<<B_*M_*D_/256, 256, 0, stream>>>(mk, mv, kbuf, vbuf);
            attn_k<<<dim3(T_/QR, H_, B_), 256, 0, stream>>>(qbuf, kbuf, vbuf, seqlen, attno);
            mgemm_k<false,false,false,false,false><<<dim3(D_/MBN, BT_/MBM, 1), 256, 0, stream>>>(
                attno, D_, wo, nullptr, tmpo, D_, BT_, D_, D_, nullptr, nullptr, nullptr, 0);
            ln_k<<<BT_/4, 256, 0, stream>>>(tmpo, g, bb, curB);
        }
    }

    mgemm_k<false,false,false,false,true><<<dim3(OUT_/MBN, BT_/MBM, 1), 256, 0, stream>>>(
        curB, D_, out_w, out_b, out0, OUT_, BT_, OUT_, D_,
        nullptr, nullptr, nullptr, 0);
    aux_k<<<1, 64, 0, stream>>>(impA, out2);
}

// Round 2
// 2720.094 us; speedup vs baseline: 1.3740x; 1.1260x over previous
//
#include <hip/hip_runtime.h>
#include <hip/hip_bf16.h>

// ============================================================================
// Net_72662256713812 — round 5: kill the router atomic serialization.
//  - rocprof r4: routerall_k = 393us, VALU 1.6%, HBM 0.2% -> pure atomic
//    serialization: 2048 tokens x 32 atomicAdd all on ONE cacheline (impA).
//  - fix: per-block LDS reduce -> plain-store partials impPart[512][32];
//    aux_k (256 thr) reduces partials deterministically + computes cv^2.
//  - zero_k launch removed (no atomic accumulator to clear).
// ============================================================================

typedef __bf16 bf16x8 __attribute__((ext_vector_type(8)));
typedef float f32x4 __attribute__((ext_vector_type(4)));

#define B_ 4
#define T_ 512
#define IN_ 80
#define OUT_ 4096
#define D_ 512
#define HID_ 1024
#define E_ 4
#define H_ 8
#define DH_ 64
#define M_ 64
#define BT_ (B_ * T_)        // 2048
#define TKV_ (T_ + M_)       // 576
#define RBLK_ (BT_ / 4)      // 512 router blocks

// ---------------------------------------------------------------- embed w1 (f32, K=80)
__global__ __launch_bounds__(256) void gemm80_k(
    const float* __restrict__ A,    // [BT_][80]
    const float* __restrict__ Bw,   // [80][1024]
    const float* __restrict__ bias, // [1024]
    float* __restrict__ C)          // [BT_][1024]
{
    __shared__ float As[80][68];   // [k][m]
    __shared__ float Bs[80][68];   // [k][n]
    int m0 = blockIdx.y * 64, n0 = blockIdx.x * 64;
    int tid = threadIdx.x;
#pragma unroll
    for (int i = 0; i < 5; i++) {
        int idx = tid + 256 * i;          // 0..1279
        int m = idx / 20, c = idx % 20;
        float4 f = *(const float4*)&A[(size_t)(m0 + m) * 80 + c * 4];
        As[c * 4 + 0][m] = f.x; As[c * 4 + 1][m] = f.y;
        As[c * 4 + 2][m] = f.z; As[c * 4 + 3][m] = f.w;
    }
#pragma unroll
    for (int i = 0; i < 5; i++) {
        int idx = tid + 256 * i;
        int k = idx / 16, c = idx % 16;
        float4 f = *(const float4*)&Bw[(size_t)k * 1024 + n0 + c * 4];
        *(float4*)&Bs[k][c * 4] = f;
    }
    __syncthreads();
    int tx = tid & 15, ty = tid >> 4;
    float acc[4][4];
#pragma unroll
    for (int j = 0; j < 4; j++)
#pragma unroll
        for (int i = 0; i < 4; i++) acc[j][i] = 0.f;
#pragma unroll 8
    for (int k = 0; k < 80; k++) {
        float4 a = *(const float4*)&As[k][ty * 4];
        float4 b = *(const float4*)&Bs[k][tx * 4];
        float av[4] = {a.x, a.y, a.z, a.w};
        float bv[4] = {b.x, b.y, b.z, b.w};
#pragma unroll
        for (int j = 0; j < 4; j++)
#pragma unroll
            for (int i = 0; i < 4; i++) acc[j][i] += av[j] * bv[i];
    }
#pragma unroll
    for (int j = 0; j < 4; j++) {
        size_t row = (size_t)(m0 + ty * 4 + j);
        float4 o;
        o.x = fmaxf(acc[j][0] + bias[n0 + tx * 4 + 0], 0.f);
        o.y = fmaxf(acc[j][1] + bias[n0 + tx * 4 + 1], 0.f);
        o.z = fmaxf(acc[j][2] + bias[n0 + tx * 4 + 2], 0.f);
        o.w = fmaxf(acc[j][3] + bias[n0 + tx * 4 + 3], 0.f);
        *(float4*)&C[row * 1024 + n0 + tx * 4] = o;
    }
}

// ---------------------------------------------------------------- R2 = emb_w2 @ router_l (f64 accum)
__global__ void wr2_k(const float* __restrict__ w2,   // [1024][512]
                      const float* __restrict__ r0,   // [512][4]
                      const float* __restrict__ rl,   // [7][512][4]
                      float* __restrict__ R2)         // [8][1024][4]
{
    int wv = threadIdx.x >> 6, lane = threadIdx.x & 63;
    int h = blockIdx.x * 4 + wv;
    const float* wrow = w2 + (size_t)h * 512;
    float w[8];
#pragma unroll
    for (int i = 0; i < 8; i++) w[i] = wrow[lane + 64 * i];
    for (int l = 0; l < 8; l++) {
        const float* rp = (l == 0) ? r0 : rl + (size_t)(l - 1) * 2048;
        double a0 = 0, a1 = 0, a2 = 0, a3 = 0;
#pragma unroll
        for (int i = 0; i < 8; i++) {
            int d = lane + 64 * i;
            float4 r = *(const float4*)&rp[d * 4];
            a0 += (double)w[i] * (double)r.x;
            a1 += (double)w[i] * (double)r.y;
            a2 += (double)w[i] * (double)r.z;
            a3 += (double)w[i] * (double)r.w;
        }
        for (int off = 32; off; off >>= 1) {
            a0 += __shfl_xor(a0, off); a1 += __shfl_xor(a1, off);
            a2 += __shfl_xor(a2, off); a3 += __shfl_xor(a3, off);
        }
        if (lane == 0) {
            float4 o = make_float4((float)a0, (float)a1, (float)a2, (float)a3);
            *(float4*)&R2[((size_t)l * 1024 + h) * 4] = o;
        }
    }
}

// ---------------------------------------------------------------- all-layers routing from h
// No global atomics: per-block LDS reduce -> plain-store partials.
__global__ __launch_bounds__(256) void routerall_k(
    const float* __restrict__ h,    // [BT_][1024]
    const float* __restrict__ R2,   // [8][1024][4]
    const int* __restrict__ seq_len,
    int* __restrict__ eid,          // [8][BT_]
    float* __restrict__ gatev,      // [8][BT_]
    float* __restrict__ impPart)    // [RBLK_][32]
{
    __shared__ float impLoc[4][32];
    int wv = threadIdx.x >> 6, lane = threadIdx.x & 63;
    int tok = blockIdx.x * 4 + wv;
    const float* hr = h + (size_t)tok * 1024;
    float acc[8][4];
#pragma unroll
    for (int l = 0; l < 8; l++)
#pragma unroll
        for (int e = 0; e < 4; e++) acc[l][e] = 0.f;
    for (int i = 0; i < 16; i++) {
        int d = lane + 64 * i;
        float hv = hr[d];
#pragma unroll
        for (int l = 0; l < 8; l++) {
            float4 r = *(const float4*)&R2[((size_t)l * 1024 + d) * 4];
            acc[l][0] += hv * r.x; acc[l][1] += hv * r.y;
            acc[l][2] += hv * r.z; acc[l][3] += hv * r.w;
        }
    }
    for (int off = 32; off; off >>= 1) {
#pragma unroll
        for (int l = 0; l < 8; l++)
#pragma unroll
            for (int e = 0; e < 4; e++) acc[l][e] += __shfl_xor(acc[l][e], off);
    }
    if (lane == 0) {
        int b = tok >> 9, t = tok & 511;
        bool valid = t < seq_len[b];
        for (int l = 0; l < 8; l++) {
            float lg[4] = {acc[l][0], acc[l][1], acc[l][2], acc[l][3]};
            float mx = fmaxf(fmaxf(lg[0], lg[1]), fmaxf(lg[2], lg[3]));
            float g[4], s = 0.f;
            for (int e = 0; e < 4; e++) { g[e] = expf(lg[e] - mx); s += g[e]; }
            float inv = 1.f / s;
            int am = 0; float bv = g[0];
            for (int e = 1; e < 4; e++) if (g[e] > bv) { bv = g[e]; am = e; }
            eid[l * BT_ + tok] = am;
            gatev[l * BT_ + tok] = bv * inv;
            for (int e = 0; e < 4; e++)
                impLoc[wv][l * 4 + e] = valid ? g[e] * inv : 0.f;
        }
    }
    __syncthreads();
    int tid = threadIdx.x;
    if (tid < 32) {
        float s = impLoc[0][tid] + impLoc[1][tid] + impLoc[2][tid] + impLoc[3][tid];
        impPart[(size_t)blockIdx.x * 32 + tid] = s;
    }
}

// ---------------------------------------------------------------- MFMA GEMM
#define MBM 128
#define MBN 64
#define MBK 32
#define LDAS 40   // bf16 elems per LDS row (32 + 8 pad; 80B = 16B-multiple)

__device__ __forceinline__ unsigned pk2(float a, float b) {
    unsigned short ua = __builtin_bit_cast(unsigned short, (__bf16)a);
    unsigned short ub = __builtin_bit_cast(unsigned short, (__bf16)b);
    return (unsigned)ua | ((unsigned)ub << 16);
}

template<bool EXPERT, bool GATHER, bool SCATTER, bool RELU, bool BIAS>
__global__ __launch_bounds__(256) void mgemm_k(
    const float* __restrict__ A, int lda,
    const float* __restrict__ Bw,         // [K,N] row-major (+ e*K*N if EXPERT)
    const float* __restrict__ bias,
    float* __restrict__ C, int ldc, int M, int N, int K,
    const int* __restrict__ seg, const int* __restrict__ sorted,
    const float* __restrict__ scale, int remM)
{
    __shared__ __align__(16) __bf16 As[MBM * LDAS];
    __shared__ __align__(16) __bf16 Bs[MBN * LDAS];

    int e = EXPERT ? blockIdx.z : 0;
    int row0 = 0, cnt = M;
    if (EXPERT) { row0 = seg[e]; cnt = seg[e + 1] - row0; }
    int m0 = blockIdx.y * MBM;
    if (m0 >= cnt) return;
    int n0 = blockIdx.x * MBN;
    const float* Bp = Bw + (EXPERT ? (size_t)e * K * N : 0);

    int tid = threadIdx.x;
    int arow = tid >> 1, ahalf = tid & 1;
    const float* aptr;
    {
        int m = m0 + arow;
        int srow;
        if (EXPERT) { int mm = (m < cnt) ? m : (cnt - 1); int ci = row0 + mm;
                      srow = GATHER ? sorted[ci] : ci; }
        else srow = m;
        aptr = A + (size_t)srow * lda + ahalf * 16;
    }
    int asw = (arow >> 3) & 3;
    int bn = tid & 63, bkc = tid >> 6;
    int bcs = bkc ^ ((bn >> 3) & 3);

    int lane = tid & 63, wid = tid >> 6;
    int wm = wid & 1, wn = wid >> 1;
    int l15 = lane & 15, quad = lane >> 4;

    int aoff[4], boff[2];
#pragma unroll
    for (int mt = 0; mt < 4; mt++) {
        int m = wm * 64 + mt * 16 + l15;
        aoff[mt] = m * LDAS + (quad ^ ((m >> 3) & 3)) * 8;
    }
#pragma unroll
    for (int nt = 0; nt < 2; nt++) {
        int n = wn * 32 + nt * 16 + l15;
        boff[nt] = n * LDAS + (quad ^ ((n >> 3) & 3)) * 8;
    }

    f32x4 acc[4][2];
#pragma unroll
    for (int mt = 0; mt < 4; mt++)
#pragma unroll
        for (int nt = 0; nt < 2; nt++)
#pragma unroll
            for (int r = 0; r < 4; r++) acc[mt][nt][r] = 0.f;

    for (int k0 = 0; k0 < K; k0 += MBK) {
#pragma unroll
        for (int cc = 0; cc < 2; cc++) {
            int kbase = k0 + ahalf * 16 + cc * 8;
            float4 f0, f1;
            if (kbase < K) {
                f0 = *(const float4*)(aptr + k0 + cc * 8);
                f1 = *(const float4*)(aptr + k0 + cc * 8 + 4);
            } else {
                f0 = make_float4(0.f, 0.f, 0.f, 0.f); f1 = f0;
            }
            uint4 pk = make_uint4(pk2(f0.x, f0.y), pk2(f0.z, f0.w),
                                  pk2(f1.x, f1.y), pk2(f1.z, f1.w));
            int cs = (ahalf * 2 + cc) ^ asw;
            *(uint4*)&As[arow * LDAS + cs * 8] = pk;
        }
        {
            float f[8];
            int kk = k0 + bkc * 8;
#pragma unroll
            for (int i = 0; i < 8; i++) {
                int k = kk + i;
                f[i] = (k < K) ? Bp[(size_t)k * N + n0 + bn] : 0.f;
            }
            uint4 pk = make_uint4(pk2(f[0], f[1]), pk2(f[2], f[3]),
                                  pk2(f[4], f[5]), pk2(f[6], f[7]));
            *(uint4*)&Bs[bn * LDAS + bcs * 8] = pk;
        }
        __syncthreads();
        bf16x8 af[4], bfm[2];
#pragma unroll
        for (int mt = 0; mt < 4; mt++) af[mt] = *(const bf16x8*)&As[aoff[mt]];
#pragma unroll
        for (int nt = 0; nt < 2; nt++) bfm[nt] = *(const bf16x8*)&Bs[boff[nt]];
#pragma unroll
        for (int mt = 0; mt < 4; mt++)
#pragma unroll
            for (int nt = 0; nt < 2; nt++)
                acc[mt][nt] = __builtin_amdgcn_mfma_f32_16x16x32_bf16(
                    af[mt], bfm[nt], acc[mt][nt], 0, 0, 0);
        __syncthreads();
    }

#pragma unroll
    for (int mt = 0; mt < 4; mt++) {
#pragma unroll
        for (int r = 0; r < 4; r++) {
            int mi = wm * 64 + mt * 16 + quad * 4 + r;
            int m = m0 + mi;
            if (EXPERT && m >= cnt) continue;
            size_t crow; float sc = 1.f;
            if (SCATTER) { int tok = sorted[row0 + m]; crow = (size_t)tok; sc = scale[tok]; }
            else if (EXPERT) crow = (size_t)(row0 + m);
            else { crow = (size_t)m; if (remM) crow = (size_t)m + (size_t)(m >> 9) * remM; }
#pragma unroll
            for (int nt = 0; nt < 2; nt++) {
                int col = n0 + wn * 32 + nt * 16 + l15;
                float v = acc[mt][nt][r];
                if (BIAS) v += bias[(EXPERT ? (size_t)e * N : 0) + col];
                if (RELU) v = fmaxf(v, 0.f);
                if (SCATTER) v *= sc;
                C[crow * (size_t)ldc + col] = v;
            }
        }
    }
}

// ---------------------------------------------------------------- fused QKV MFMA GEMM
__global__ __launch_bounds__(256) void qkv_k(
    const float* __restrict__ A,          // [BT_][512]
    const float* __restrict__ wq, const float* __restrict__ wk,
    const float* __restrict__ wv,
    float* __restrict__ qo, float* __restrict__ ko, float* __restrict__ vo)
{
    __shared__ __align__(16) __bf16 As[MBM * LDAS];
    __shared__ __align__(16) __bf16 Bs[MBN * LDAS];

    int n0g = blockIdx.x * MBN;
    int which = n0g >> 9;
    int n0 = n0g & 511;
    const float* Bp = (which == 0) ? wq : (which == 1) ? wk : wv;
    float* Cp = (which == 0) ? qo : (which == 1) ? ko : vo;
    int m0 = blockIdx.y * MBM;

    int tid = threadIdx.x;
    int arow = tid >> 1, ahalf = tid & 1;
    const float* aptr = A + (size_t)(m0 + arow) * D_ + ahalf * 16;
    int asw = (arow >> 3) & 3;
    int bn = tid & 63, bkc = tid >> 6;
    int bcs = bkc ^ ((bn >> 3) & 3);

    int lane = tid & 63, wid = tid >> 6;
    int wm = wid & 1, wn = wid >> 1;
    int l15 = lane & 15, quad = lane >> 4;

    int aoff[4], boff[2];
#pragma unroll
    for (int mt = 0; mt < 4; mt++) {
        int m = wm * 64 + mt * 16 + l15;
        aoff[mt] = m * LDAS + (quad ^ ((m >> 3) & 3)) * 8;
    }
#pragma unroll
    for (int nt = 0; nt < 2; nt++) {
        int n = wn * 32 + nt * 16 + l15;
        boff[nt] = n * LDAS + (quad ^ ((n >> 3) & 3)) * 8;
    }

    f32x4 acc[4][2];
#pragma unroll
    for (int mt = 0; mt < 4; mt++)
#pragma unroll
        for (int nt = 0; nt < 2; nt++)
#pragma unroll
            for (int r = 0; r < 4; r++) acc[mt][nt][r] = 0.f;

    for (int k0 = 0; k0 < D_; k0 += MBK) {
#pragma unroll
        for (int cc = 0; cc < 2; cc++) {
            float4 f0 = *(const float4*)(aptr + k0 + cc * 8);
            float4 f1 = *(const float4*)(aptr + k0 + cc * 8 + 4);
            uint4 pk = make_uint4(pk2(f0.x, f0.y), pk2(f0.z, f0.w),
                                  pk2(f1.x, f1.y), pk2(f1.z, f1.w));
            int cs = (ahalf * 2 + cc) ^ asw;
            *(uint4*)&As[arow * LDAS + cs * 8] = pk;
        }
        {
            float f[8];
            int kk = k0 + bkc * 8;
#pragma unroll
            for (int i = 0; i < 8; i++)
                f[i] = Bp[(size_t)(kk + i) * D_ + n0 + bn];
            uint4 pk = make_uint4(pk2(f[0], f[1]), pk2(f[2], f[3]),
                                  pk2(f[4], f[5]), pk2(f[6], f[7]));
            *(uint4*)&Bs[bn * LDAS + bcs * 8] = pk;
        }
        __syncthreads();
        bf16x8 af[4], bfm[2];
#pragma unroll
        for (int mt = 0; mt < 4; mt++) af[mt] = *(const bf16x8*)&As[aoff[mt]];
#pragma unroll
        for (int nt = 0; nt < 2; nt++) bfm[nt] = *(const bf16x8*)&Bs[boff[nt]];
#pragma unroll
        for (int mt = 0; mt < 4; mt++)
#pragma unroll
            for (int nt = 0; nt < 2; nt++)
                acc[mt][nt] = __builtin_amdgcn_mfma_f32_16x16x32_bf16(
                    af[mt], bfm[nt], acc[mt][nt], 0, 0, 0);
        __syncthreads();
    }

#pragma unroll
    for (int mt = 0; mt < 4; mt++) {
#pragma unroll
        for (int r = 0; r < 4; r++) {
            int mi = wm * 64 + mt * 16 + quad * 4 + r;
            int m = m0 + mi;
            size_t crow = which ? (size_t)(m + (m >> 9) * M_) : (size_t)m;
#pragma unroll
            for (int nt = 0; nt < 2; nt++) {
                int col = n0 + wn * 32 + nt * 16 + l15;
                Cp[crow * (size_t)D_ + col] = acc[mt][nt][r];
            }
        }
    }
}

// ---------------------------------------------------------------- small ops
__global__ void bucketall_k(const int* __restrict__ eidA, int* __restrict__ sortedA,
                            int* __restrict__ segA)
{
    __shared__ int cnt[E_]; __shared__ int cur[E_];
    int l = blockIdx.x;
    const int* eid = eidA + l * BT_;
    int* sorted = sortedA + l * BT_;
    int* seg = segA + l * 8;
    int tid = threadIdx.x;
    if (tid < E_) cnt[tid] = 0;
    __syncthreads();
    for (int t = tid; t < BT_; t += 256) atomicAdd(&cnt[eid[t]], 1);
    __syncthreads();
    if (tid == 0) {
        int o = 0;
        for (int e = 0; e < E_; e++) { seg[e] = o; cur[e] = o; o += cnt[e]; }
        seg[E_] = o;
    }
    __syncthreads();
    for (int t = tid; t < BT_; t += 256) {
        int pos = atomicAdd(&cur[eid[t]], 1);
        sorted[pos] = t;
    }
}

__global__ void fsmn_k(const float* __restrict__ p, const float* __restrict__ fb,
                       const float* __restrict__ fa, float* __restrict__ cur, int skip)
{
    int idx = blockIdx.x * 256 + threadIdx.x;
    int d = idx & 511;
    int t = (idx >> 9) & 511;
    float m = p[idx];
#pragma unroll
    for (int k = 0; k < 4; k++) {
        int tt = t - 2 * (k + 1);
        if (tt >= 0) m += fb[k * D_ + d] * p[idx - D_ * 2 * (k + 1)];
    }
    if (t + 1 < T_) m += fa[d] * p[idx + D_];
    if (skip) m += cur[idx];
    cur[idx] = m;
}

__global__ void addpe_k(float* __restrict__ cur) {
    int idx = blockIdx.x * 256 + threadIdx.x;
    int d = idx & 511, t = (idx >> 9) & 511;
    float div = expf((float)(d & ~1) * (-9.210340371976184f / (float)D_));
    float ang = (float)t * div;
    cur[idx] += (d & 1) ? cosf(ang) : sinf(ang);
}

__global__ void fillmem_k(const float* __restrict__ mk, const float* __restrict__ mv,
                          float* __restrict__ kbuf, float* __restrict__ vbuf)
{
    int idx = blockIdx.x * 256 + threadIdx.x;
    int d = idx & 511, m = (idx >> 9) & 63, b = idx >> 15;
    size_t row = (size_t)b * TKV_ + T_ + m;
    kbuf[row * D_ + d] = mk[m * D_ + d];
    vbuf[row * D_ + d] = mv[m * D_ + d];
}

// attention: one block = (b, h, 16 q rows); 4 rows per wave
#define QR 16
__global__ __launch_bounds__(256) void attn_k(
    const float* __restrict__ q, const float* __restrict__ kbuf,
    const float* __restrict__ vbuf, const int* __restrict__ seq_len,
    float* __restrict__ attno)
{
    __shared__ float kv[64 * 69];
    __shared__ float qs[QR][64];
    __shared__ float sc[QR][TKV_];
    int b = blockIdx.z, h = blockIdx.y, t0 = blockIdx.x * QR;
    int tid = threadIdx.x, w = tid >> 6, lane = tid & 63;
    int r0 = w * 4;
#pragma unroll
    for (int i = 0; i < 4; i++) {
        int idx = tid + 256 * i;
        int r = idx >> 6, d = idx & 63;
        qs[r][d] = q[((size_t)(b * T_) + t0 + r) * D_ + h * DH_ + d] * 0.125f;
    }
    int sl = seq_len[b];
    for (int s0 = 0; s0 < TKV_; s0 += 64) {
        __syncthreads();
#pragma unroll
        for (int i = 0; i < 16; i++) {
            int idx = tid + 256 * i;
            int key = idx >> 6, d = idx & 63;
            kv[d * 69 + key] = kbuf[((size_t)b * TKV_ + s0 + key) * D_ + h * DH_ + d];
        }
        __syncthreads();
        float a0 = 0, a1 = 0, a2 = 0, a3 = 0;
#pragma unroll 4
        for (int d = 0; d < 64; d++) {
            float kvv = kv[d * 69 + lane];
            a0 += qs[r0 + 0][d] * kvv;
            a1 += qs[r0 + 1][d] * kvv;
            a2 += qs[r0 + 2][d] * kvv;
            a3 += qs[r0 + 3][d] * kvv;
        }
        int sa = s0 + lane;
        bool ok = (sa >= T_ || sa < sl);
        sc[r0 + 0][sa] = ok ? a0 : -1e9f;
        sc[r0 + 1][sa] = ok ? a1 : -1e9f;
        sc[r0 + 2][sa] = ok ? a2 : -1e9f;
        sc[r0 + 3][sa] = ok ? a3 : -1e9f;
    }
    float inv[4];
#pragma unroll
    for (int r = 0; r < 4; r++) {
        float mx = -1e30f;
        for (int s = lane; s < TKV_; s += 64) mx = fmaxf(mx, sc[r0 + r][s]);
        for (int off = 32; off; off >>= 1) mx = fmaxf(mx, __shfl_xor(mx, off));
        float sum = 0.f;
        for (int s = lane; s < TKV_; s += 64) {
            float e2 = expf(sc[r0 + r][s] - mx); sc[r0 + r][s] = e2; sum += e2;
        }
        for (int off = 32; off; off >>= 1) sum += __shfl_xor(sum, off);
        inv[r] = 1.f / sum;
    }
    float o0 = 0, o1 = 0, o2 = 0, o3 = 0;
    for (int s0 = 0; s0 < TKV_; s0 += 64) {
        __syncthreads();
#pragma unroll
        for (int i = 0; i < 16; i++) {
            int idx = tid + 256 * i;
            int key = idx >> 6, d = idx & 63;
            kv[key * 69 + d] = vbuf[((size_t)b * TKV_ + s0 + key) * D_ + h * DH_ + d];
        }
        __syncthreads();
#pragma unroll 4
        for (int j = 0; j < 64; j++) {
            float vv = kv[j * 69 + lane];
            o0 += sc[r0 + 0][s0 + j] * vv;
            o1 += sc[r0 + 1][s0 + j] * vv;
            o2 += sc[r0 + 2][s0 + j] * vv;
            o3 += sc[r0 + 3][s0 + j] * vv;
        }
    }
    size_t base = ((size_t)(b * T_) + t0 + r0) * D_ + h * DH_ + lane;
    attno[base + 0 * D_] = o0 * inv[0];
    attno[base + 1 * D_] = o1 * inv[1];
    attno[base + 2 * D_] = o2 * inv[2];
    attno[base + 3 * D_] = o3 * inv[3];
}

__global__ void ln_k(const float* __restrict__ o, const float* __restrict__ g,
                     const float* __restrict__ bb, float* __restrict__ cur)
{
    int w = threadIdx.x >> 6, lane = threadIdx.x & 63;
    size_t row = (size_t)(blockIdx.x * 4 + w);
    float v[8]; float s = 0.f;
#pragma unroll
    for (int i = 0; i < 8; i++) {
        int d = lane + 64 * i;
        v[i] = cur[row * D_ + d] + o[row * D_ + d];
        s += v[i];
    }
    for (int off = 32; off; off >>= 1) s += __shfl_xor(s, off);
    float mu = s * (1.f / D_);
    float vs = 0.f;
#pragma unroll
    for (int i = 0; i < 8; i++) { float dd = v[i] - mu; vs += dd * dd; }
    for (int off = 32; off; off >>= 1) vs += __shfl_xor(vs, off);
    float rstd = rsqrtf(vs * (1.f / D_) + 1e-5f);
#pragma unroll
    for (int i = 0; i < 8; i++) {
        int d = lane + 64 * i;
        cur[row * D_ + d] = (v[i] - mu) * rstd * g[d] + bb[d];
    }
}

// reduce impPart[RBLK_][32] -> imp[8][4], then cv^2 sum (deterministic)
__global__ __launch_bounds__(256) void aux_k(const float* __restrict__ impPart,
                                             float* __restrict__ outp)
{
    __shared__ float red[8][32];
    __shared__ float imp[32];
    int tid = threadIdx.x;
    int c = tid & 31, p = tid >> 5;
    float s = 0.f;
    for (int b = p; b < RBLK_; b += 8) s += impPart[(size_t)b * 32 + c];
    red[p][c] = s;
    __syncthreads();
    if (tid < 32) {
        float t = 0.f;
#pragma unroll
        for (int i = 0; i < 8; i++) t += red[i][tid];
        imp[tid] = t;
    }
    __syncthreads();
    if (tid == 0) {
        float total = 0.f;
        for (int l = 0; l < 8; l++) {
            const float* ip = imp + l * 4;
            float m = (ip[0] + ip[1] + ip[2] + ip[3]) * 0.25f;
            float var = 0.f;
            for (int e = 0; e < 4; e++) { float d = ip[e] - m; var += d * d; }
            var *= 0.25f;
            total += var / (m * m + 1e-9f);
        }
        *outp = total;
    }
}

// ============================================================================
extern "C" void kernel_launch(void* const* d_in, const int* in_sizes, int n_in,
                              void* d_out, int out_size, void* d_ws, size_t ws_size,
                              hipStream_t stream)
{
    (void)in_sizes; (void)n_in; (void)out_size; (void)ws_size;
    const float* x        = (const float*)d_in[0];
    const int*   seqlen   = (const int*)d_in[1];
    const float* emb_w1   = (const float*)d_in[2];
    const float* emb_b1   = (const float*)d_in[3];
    const float* emb_w2   = (const float*)d_in[4];
    const float* emb_wo   = (const float*)d_in[5];
    const float* f0_w1    = (const float*)d_in[6];
    const float* f0_b1    = (const float*)d_in[7];
    const float* f0_w2    = (const float*)d_in[8];
    const float* f0_router= (const float*)d_in[9];
    const float* f0_fb    = (const float*)d_in[10];
    const float* f0_fa    = (const float*)d_in[11];
    const float* f_w1     = (const float*)d_in[12];
    const float* f_b1     = (const float*)d_in[13];
    const float* f_w2     = (const float*)d_in[14];
    const float* f_router = (const float*)d_in[15];
    const float* f_fb     = (const float*)d_in[16];
    const float* f_fa     = (const float*)d_in[17];
    const float* attn_wq  = (const float*)d_in[18];
    const float* attn_wk  = (const float*)d_in[19];
    const float* attn_wv  = (const float*)d_in[20];
    const float* attn_wo  = (const float*)d_in[21];
    const float* attn_mk  = (const float*)d_in[22];
    const float* attn_mv  = (const float*)d_in[23];
    const float* ln_g     = (const float*)d_in[24];
    const float* ln_b     = (const float*)d_in[25];
    const float* out_w    = (const float*)d_in[26];
    const float* out_b    = (const float*)d_in[27];

    float* out0 = (float*)d_out;
    float* out1 = out0 + (size_t)BT_ * OUT_;
    float* out2 = out1 + (size_t)BT_ * OUT_;

    float* fws = (float*)d_ws;
    size_t o = 0;
    float* embedF = fws + o; o += (size_t)BT_ * D_;
    float* curB   = fws + o; o += (size_t)BT_ * D_;
    float* hbuf   = fws + o; o += (size_t)BT_ * HID_;
    float* pbuf   = fws + o; o += (size_t)BT_ * D_;
    float* kbuf   = fws + o; o += (size_t)B_ * TKV_ * D_;
    float* vbuf   = fws + o; o += (size_t)B_ * TKV_ * D_;
    float* gatev  = fws + o; o += (size_t)8 * BT_;
    float* impPart= fws + o; o += (size_t)RBLK_ * 32;
    float* R2     = fws + o; o += (size_t)8 * 1024 * 4;
    int* eid     = (int*)(fws + o); o += (size_t)8 * BT_;
    int* sortedA = (int*)(fws + o); o += (size_t)8 * BT_;
    int* segA    = (int*)(fws + o); o += 64;
    float* qbuf  = pbuf;
    float* attno = hbuf;
    float* tmpo  = hbuf + (size_t)BT_ * D_;

    // h = relu(x@emb_w1+b1) — exact f32 (feeds routing), fast K=80 kernel
    gemm80_k<<<dim3(HID_ / 64, BT_ / 64, 1), 256, 0, stream>>>(x, emb_w1, emb_b1, hbuf);
    // R2[l] = emb_w2 @ router_l in f64 — routing reassociation adds ~0 error
    wr2_k<<<256, 256, 0, stream>>>(emb_w2, f0_router, f_router, R2);
    // all 8 layers' routing decisions in one pass over h (no global atomics)
    routerall_k<<<RBLK_, 256, 0, stream>>>(hbuf, R2, seqlen, eid, gatev, impPart);
    // all 8 bucket sorts, one dispatch
    bucketall_k<<<8, 256, 0, stream>>>(eid, sortedA, segA);
    // embedF only feeds embed_out now -> bf16 MFMA is fine
    mgemm_k<false,false,false,false,false><<<dim3(D_/MBN, BT_/MBM, 1), 256, 0, stream>>>(
        hbuf, HID_, emb_w2, nullptr, embedF, D_, BT_, D_, HID_,
        nullptr, nullptr, nullptr, 0);
    mgemm_k<false,false,false,false,false><<<dim3(OUT_/MBN, BT_/MBM, 1), 256, 0, stream>>>(
        embedF, D_, emb_wo, nullptr, out1, OUT_, BT_, OUT_, D_,
        nullptr, nullptr, nullptr, 0);

    for (int l = 0; l < 8; l++) {
        const float* w1  = (l == 0) ? f0_w1 : f_w1 + (size_t)(l-1) * E_ * D_ * HID_;
        const float* b1p = (l == 0) ? f0_b1 : f_b1 + (size_t)(l-1) * E_ * HID_;
        const float* w2  = (l == 0) ? f0_w2 : f_w2 + (size_t)(l-1) * E_ * HID_ * D_;
        const float* fbp = (l == 0) ? f0_fb : f_fb + (size_t)(l-1) * 4 * D_;
        const float* fap = (l == 0) ? f0_fa : f_fa + (size_t)(l-1) * 1 * D_;
        int Kl = (l == 0) ? IN_ : D_;
        const float* Ain = (l == 0) ? x : curB;
        const int* seg = segA + l * 8;
        const int* sorted = sortedA + l * BT_;

        mgemm_k<true,true,false,true,true><<<dim3(HID_/MBN, BT_/MBM, E_), 256, 0, stream>>>(
            Ain, Kl, w1, b1p, hbuf, HID_, BT_, HID_, Kl, seg, sorted, nullptr, 0);
        mgemm_k<true,false,true,false,false><<<dim3(D_/MBN, BT_/MBM, E_), 256, 0, stream>>>(
            hbuf, HID_, w2, nullptr, pbuf, D_, BT_, D_, HID_, seg, sorted,
            gatev + l * BT_, 0);
        fsmn_k<<<BT_*D_/256, 256, 0, stream>>>(pbuf, fbp, fap, curB, (l > 0) ? 1 : 0);

        if (l == 3) addpe_k<<<BT_*D_/256, 256, 0, stream>>>(curB);

        if (l == 3 || l == 7) {
            int ab = (l == 3) ? 0 : 1;
            const float* wq = attn_wq + (size_t)ab * D_ * D_;
            const float* wk = attn_wk + (size_t)ab * D_ * D_;
            const float* wv = attn_wv + (size_t)ab * D_ * D_;
            const float* wo = attn_wo + (size_t)ab * D_ * D_;
            const float* mk = attn_mk + (size_t)ab * M_ * D_;
            const float* mv = attn_mv + (size_t)ab * M_ * D_;
            const float* g  = ln_g + (size_t)ab * D_;
            const float* bb = ln_b + (size_t)ab * D_;

            qkv_k<<<dim3(3 * D_ / MBN, BT_ / MBM, 1), 256, 0, stream>>>(
                curB, wq, wk, wv, qbuf, kbuf, vbuf);
            fillmem_k<<<B_*M_*D_/256, 256, 0, stream>>>(mk, mv, kbuf, vbuf);
            attn_k<<<dim3(T_/QR, H_, B_), 256, 0, stream>>>(qbuf, kbuf, vbuf, seqlen, attno);
            mgemm_k<false,false,false,false,false><<<dim3(D_/MBN, BT_/MBM, 1), 256, 0, stream>>>(
                attno, D_, wo, nullptr, tmpo, D_, BT_, D_, D_, nullptr, nullptr, nullptr, 0);
            ln_k<<<BT_/4, 256, 0, stream>>>(tmpo, g, bb, curB);
        }
    }

    mgemm_k<false,false,false,false,true><<<dim3(OUT_/MBN, BT_/MBM, 1), 256, 0, stream>>>(
        curB, D_, out_w, out_b, out0, OUT_, BT_, OUT_, D_,
        nullptr, nullptr, nullptr, 0);
    aux_k<<<1, 256, 0, stream>>>(impPart, out2);
}

// Round 4
// 1422.927 us; speedup vs baseline: 2.6265x; 1.9116x over previous
//
#include <hip/hip_runtime.h>
#include <hip/hip_bf16.h>

// ============================================================================
// Net_72662256713812 — round 7: round-6 expert-GEMM rewrite, bug-fixed.
//  - r6 postmortem: (a) workspace grew 34.8->49.5MB (likely OOB fault ->
//    container death); (b) egemm B staged [k][n] but read [n][k] (garbage);
//    (c) egemm A pointer missed +row0. All three fixed.
//  - workspace aliasing: Ag+hbufh live in hbuf (dead after routing);
//    w1h/w2h live in kbuf/vbuf (dead until post-expert attention phase).
//    Total = round-5's proven 34.8 MB.
//  - egemm_k: bf16 in, dbuf LDS, issue-early/write-late staging, MBK=64,
//    XOR chunk swizzle; B staged with transpose (coalesced ushort loads).
// ============================================================================

typedef __bf16 bf16x8 __attribute__((ext_vector_type(8)));
typedef float f32x4 __attribute__((ext_vector_type(4)));

#define B_ 4
#define T_ 512
#define IN_ 80
#define OUT_ 4096
#define D_ 512
#define HID_ 1024
#define E_ 4
#define H_ 8
#define DH_ 64
#define M_ 64
#define BT_ (B_ * T_)        // 2048
#define TKV_ (T_ + M_)       // 576
#define RBLK_ (BT_ / 4)      // 512 router blocks

__device__ __forceinline__ unsigned pk2(float a, float b) {
    unsigned short ua = __builtin_bit_cast(unsigned short, (__bf16)a);
    unsigned short ub = __builtin_bit_cast(unsigned short, (__bf16)b);
    return (unsigned)ua | ((unsigned)ub << 16);
}
__device__ __forceinline__ unsigned pkh2(__bf16 a, __bf16 b) {
    unsigned short ua = __builtin_bit_cast(unsigned short, a);
    unsigned short ub = __builtin_bit_cast(unsigned short, b);
    return (unsigned)ua | ((unsigned)ub << 16);
}

// ---------------------------------------------------------------- embed w1 (f32, K=80)
__global__ __launch_bounds__(256) void gemm80_k(
    const float* __restrict__ A,    // [BT_][80]
    const float* __restrict__ Bw,   // [80][1024]
    const float* __restrict__ bias, // [1024]
    float* __restrict__ C)          // [BT_][1024]
{
    __shared__ float As[80][68];   // [k][m]
    __shared__ float Bs[80][68];   // [k][n]
    int m0 = blockIdx.y * 64, n0 = blockIdx.x * 64;
    int tid = threadIdx.x;
#pragma unroll
    for (int i = 0; i < 5; i++) {
        int idx = tid + 256 * i;          // 0..1279
        int m = idx / 20, c = idx % 20;
        float4 f = *(const float4*)&A[(size_t)(m0 + m) * 80 + c * 4];
        As[c * 4 + 0][m] = f.x; As[c * 4 + 1][m] = f.y;
        As[c * 4 + 2][m] = f.z; As[c * 4 + 3][m] = f.w;
    }
#pragma unroll
    for (int i = 0; i < 5; i++) {
        int idx = tid + 256 * i;
        int k = idx / 16, c = idx % 16;
        float4 f = *(const float4*)&Bw[(size_t)k * 1024 + n0 + c * 4];
        *(float4*)&Bs[k][c * 4] = f;
    }
    __syncthreads();
    int tx = tid & 15, ty = tid >> 4;
    float acc[4][4];
#pragma unroll
    for (int j = 0; j < 4; j++)
#pragma unroll
        for (int i = 0; i < 4; i++) acc[j][i] = 0.f;
#pragma unroll 8
    for (int k = 0; k < 80; k++) {
        float4 a = *(const float4*)&As[k][ty * 4];
        float4 b = *(const float4*)&Bs[k][tx * 4];
        float av[4] = {a.x, a.y, a.z, a.w};
        float bv[4] = {b.x, b.y, b.z, b.w};
#pragma unroll
        for (int j = 0; j < 4; j++)
#pragma unroll
            for (int i = 0; i < 4; i++) acc[j][i] += av[j] * bv[i];
    }
#pragma unroll
    for (int j = 0; j < 4; j++) {
        size_t row = (size_t)(m0 + ty * 4 + j);
        float4 o;
        o.x = fmaxf(acc[j][0] + bias[n0 + tx * 4 + 0], 0.f);
        o.y = fmaxf(acc[j][1] + bias[n0 + tx * 4 + 1], 0.f);
        o.z = fmaxf(acc[j][2] + bias[n0 + tx * 4 + 2], 0.f);
        o.w = fmaxf(acc[j][3] + bias[n0 + tx * 4 + 3], 0.f);
        *(float4*)&C[row * 1024 + n0 + tx * 4] = o;
    }
}

// ---------------------------------------------------------------- R2 = emb_w2 @ router_l (f64 accum)
__global__ void wr2_k(const float* __restrict__ w2,   // [1024][512]
                      const float* __restrict__ r0,   // [512][4]
                      const float* __restrict__ rl,   // [7][512][4]
                      float* __restrict__ R2)         // [8][1024][4]
{
    int wv = threadIdx.x >> 6, lane = threadIdx.x & 63;
    int h = blockIdx.x * 4 + wv;
    const float* wrow = w2 + (size_t)h * 512;
    float w[8];
#pragma unroll
    for (int i = 0; i < 8; i++) w[i] = wrow[lane + 64 * i];
    for (int l = 0; l < 8; l++) {
        const float* rp = (l == 0) ? r0 : rl + (size_t)(l - 1) * 2048;
        double a0 = 0, a1 = 0, a2 = 0, a3 = 0;
#pragma unroll
        for (int i = 0; i < 8; i++) {
            int d = lane + 64 * i;
            float4 r = *(const float4*)&rp[d * 4];
            a0 += (double)w[i] * (double)r.x;
            a1 += (double)w[i] * (double)r.y;
            a2 += (double)w[i] * (double)r.z;
            a3 += (double)w[i] * (double)r.w;
        }
        for (int off = 32; off; off >>= 1) {
            a0 += __shfl_xor(a0, off); a1 += __shfl_xor(a1, off);
            a2 += __shfl_xor(a2, off); a3 += __shfl_xor(a3, off);
        }
        if (lane == 0) {
            float4 o = make_float4((float)a0, (float)a1, (float)a2, (float)a3);
            *(float4*)&R2[((size_t)l * 1024 + h) * 4] = o;
        }
    }
}

// ---------------------------------------------------------------- all-layers routing from h
__global__ __launch_bounds__(256) void routerall_k(
    const float* __restrict__ h,    // [BT_][1024]
    const float* __restrict__ R2,   // [8][1024][4]
    const int* __restrict__ seq_len,
    int* __restrict__ eid,          // [8][BT_]
    float* __restrict__ gatev,      // [8][BT_]
    float* __restrict__ impPart)    // [RBLK_][32]
{
    __shared__ float impLoc[4][32];
    int wv = threadIdx.x >> 6, lane = threadIdx.x & 63;
    int tok = blockIdx.x * 4 + wv;
    const float* hr = h + (size_t)tok * 1024;
    float acc[8][4];
#pragma unroll
    for (int l = 0; l < 8; l++)
#pragma unroll
        for (int e = 0; e < 4; e++) acc[l][e] = 0.f;
    for (int i = 0; i < 16; i++) {
        int d = lane + 64 * i;
        float hv = hr[d];
#pragma unroll
        for (int l = 0; l < 8; l++) {
            float4 r = *(const float4*)&R2[((size_t)l * 1024 + d) * 4];
            acc[l][0] += hv * r.x; acc[l][1] += hv * r.y;
            acc[l][2] += hv * r.z; acc[l][3] += hv * r.w;
        }
    }
    for (int off = 32; off; off >>= 1) {
#pragma unroll
        for (int l = 0; l < 8; l++)
#pragma unroll
            for (int e = 0; e < 4; e++) acc[l][e] += __shfl_xor(acc[l][e], off);
    }
    if (lane == 0) {
        int b = tok >> 9, t = tok & 511;
        bool valid = t < seq_len[b];
        for (int l = 0; l < 8; l++) {
            float lg[4] = {acc[l][0], acc[l][1], acc[l][2], acc[l][3]};
            float mx = fmaxf(fmaxf(lg[0], lg[1]), fmaxf(lg[2], lg[3]));
            float g[4], s = 0.f;
            for (int e = 0; e < 4; e++) { g[e] = expf(lg[e] - mx); s += g[e]; }
            float inv = 1.f / s;
            int am = 0; float bv = g[0];
            for (int e = 1; e < 4; e++) if (g[e] > bv) { bv = g[e]; am = e; }
            eid[l * BT_ + tok] = am;
            gatev[l * BT_ + tok] = bv * inv;
            for (int e = 0; e < 4; e++)
                impLoc[wv][l * 4 + e] = valid ? g[e] * inv : 0.f;
        }
    }
    __syncthreads();
    int tid = threadIdx.x;
    if (tid < 32) {
        float s = impLoc[0][tid] + impLoc[1][tid] + impLoc[2][tid] + impLoc[3][tid];
        impPart[(size_t)blockIdx.x * 32 + tid] = s;
    }
}

// ---------------------------------------------------------------- weight f32->bf16 (+K pad)
// dst[e][k][n] (k in [0,Kpad)) = k<Ksrc ? bf16(src[e][k][n]) : 0
__global__ void cvtw_k(const float* __restrict__ src, __bf16* __restrict__ dst,
                       int nsh, int kpsh, int Ksrc)
{
    int idx = blockIdx.x * 256 + threadIdx.x;
    int cprsh = nsh - 3;
    int row = idx >> cprsh;                      // e*Kpad + k
    int chunk = idx & ((1 << cprsh) - 1);
    int e = row >> kpsh, k = row & ((1 << kpsh) - 1);
    int n = chunk * 8;
    uint4 pk;
    if (k < Ksrc) {
        const float* sp = src + (((size_t)e * Ksrc + k) << nsh) + n;
        float4 f0 = *(const float4*)sp;
        float4 f1 = *(const float4*)(sp + 4);
        pk = make_uint4(pk2(f0.x, f0.y), pk2(f0.z, f0.w),
                        pk2(f1.x, f1.y), pk2(f1.z, f1.w));
    } else pk = make_uint4(0, 0, 0, 0);
    *(uint4*)&dst[(((size_t)row) << nsh) + n] = pk;
}

// ---------------------------------------------------------------- gather A rows -> sorted-order bf16
__global__ void gathera_k(const float* __restrict__ src, int lda,
                          const int* __restrict__ sorted,
                          __bf16* __restrict__ dst, int kpsh, int Ksrc)
{
    int idx = blockIdx.x * 256 + threadIdx.x;
    int cprsh = kpsh - 3;
    int row = idx >> cprsh;
    int chunk = idx & ((1 << cprsh) - 1);
    int k0 = chunk * 8;
    uint4 pk;
    if (k0 < Ksrc) {
        const float* sp = src + (size_t)sorted[row] * lda + k0;
        float4 f0 = *(const float4*)sp;
        float4 f1 = *(const float4*)(sp + 4);
        pk = make_uint4(pk2(f0.x, f0.y), pk2(f0.z, f0.w),
                        pk2(f1.x, f1.y), pk2(f1.z, f1.w));
    } else pk = make_uint4(0, 0, 0, 0);
    *(uint4*)&dst[((size_t)row << kpsh) + k0] = pk;
}

// ---------------------------------------------------------------- pipelined expert GEMM (bf16 in)
// Ag [2048][Kpad] bf16 sorted order; Bh [E][Kpad][N] bf16.
// W1OUT: Cb bf16 [2048][N] = relu(acc+bias) (sorted order)
// else : Cf f32 scatter Cf[sorted[row0+m]][n] = acc*scale[tok]
template<bool W1OUT>
__global__ __launch_bounds__(256) void egemm_k(
    const __bf16* __restrict__ Ag, const __bf16* __restrict__ Bh,
    const float* __restrict__ bias,
    __bf16* __restrict__ Cb, float* __restrict__ Cf,
    int N, int Kpad,
    const int* __restrict__ seg, const int* __restrict__ sorted,
    const float* __restrict__ scale)
{
    __shared__ __align__(16) __bf16 As[2][128 * 64];
    __shared__ __align__(16) __bf16 Bs[2][64 * 64];

    int e = blockIdx.z;
    int row0 = seg[e], cnt = seg[e + 1] - row0;
    int m0 = blockIdx.y * 128;
    if (m0 >= cnt) return;
    int n0 = blockIdx.x * 64;
    const __bf16* Bp = Bh + (size_t)e * Kpad * N;

    int tid = threadIdx.x;
    // A staging: row = tid>>1 (local), 4 chunks of 8 bf16 at half (tid&1)
    int arow = tid >> 1, ahalf = tid & 1;
    const __bf16* aptr = Ag + (size_t)(row0 + m0 + arow) * Kpad + ahalf * 32;  // +row0 (r6 bug fixed)
    int asb = arow * 64;
    int ac0 = ahalf * 4;
    int arx = arow & 7;
    // B staging with transpose: n-col = tid&63, k-chunk group = tid>>6
    int bn = tid & 63, bkc = tid >> 6;
    const __bf16* bptr = Bp + n0 + bn;
    int bsb = bn * 64;
    int brx = bn & 7;

    int lane = tid & 63, wid = tid >> 6;
    int wm = wid & 1, wn = wid >> 1;
    int l15 = lane & 15, quad = lane >> 4;

    int aoff[4][2], boff[2][2];
#pragma unroll
    for (int mt = 0; mt < 4; mt++) {
        int m = wm * 64 + mt * 16 + l15;
#pragma unroll
        for (int s = 0; s < 2; s++)
            aoff[mt][s] = m * 64 + (((s * 4 + quad) ^ (m & 7)) * 8);
    }
#pragma unroll
    for (int nt = 0; nt < 2; nt++) {
        int n = wn * 32 + nt * 16 + l15;
#pragma unroll
        for (int s = 0; s < 2; s++)
            boff[nt][s] = n * 64 + (((s * 4 + quad) ^ (n & 7)) * 8);
    }

    f32x4 acc[4][2];
#pragma unroll
    for (int mt = 0; mt < 4; mt++)
#pragma unroll
        for (int nt = 0; nt < 2; nt++)
#pragma unroll
            for (int r = 0; r < 4; r++) acc[mt][nt][r] = 0.f;

    uint4 rA[4]; unsigned rB[8];
    auto stage = [&](int k0) {
#pragma unroll
        for (int j = 0; j < 4; j++) rA[j] = *(const uint4*)(aptr + k0 + j * 8);
#pragma unroll
        for (int c = 0; c < 2; c++) {
            int kk = k0 + (bkc * 2 + c) * 8;
#pragma unroll
            for (int i = 0; i < 4; i++)
                rB[c * 4 + i] = pkh2(bptr[(size_t)(kk + 2 * i) * N],
                                     bptr[(size_t)(kk + 2 * i + 1) * N]);
        }
    };
    auto commit = [&](int buf) {
#pragma unroll
        for (int j = 0; j < 4; j++)
            *(uint4*)&As[buf][asb + (((ac0 + j) ^ arx) * 8)] = rA[j];
#pragma unroll
        for (int c = 0; c < 2; c++)
            *(uint4*)&Bs[buf][bsb + (((bkc * 2 + c) ^ brx) * 8)] =
                make_uint4(rB[c * 4 + 0], rB[c * 4 + 1], rB[c * 4 + 2], rB[c * 4 + 3]);
    };

    stage(0); commit(0); __syncthreads();
    int nt_ = Kpad >> 6;
    for (int t = 0; t < nt_; t++) {
        int buf = t & 1;
        if (t + 1 < nt_) stage((t + 1) << 6);     // issue-early (hides under MFMA)
        bf16x8 af[4][2], bfr[2][2];
#pragma unroll
        for (int mt = 0; mt < 4; mt++)
#pragma unroll
            for (int s = 0; s < 2; s++)
                af[mt][s] = *(const bf16x8*)&As[buf][aoff[mt][s]];
#pragma unroll
        for (int ntx = 0; ntx < 2; ntx++)
#pragma unroll
            for (int s = 0; s < 2; s++)
                bfr[ntx][s] = *(const bf16x8*)&Bs[buf][boff[ntx][s]];
#pragma unroll
        for (int mt = 0; mt < 4; mt++)
#pragma unroll
            for (int ntx = 0; ntx < 2; ntx++)
#pragma unroll
                for (int s = 0; s < 2; s++)
                    acc[mt][ntx] = __builtin_amdgcn_mfma_f32_16x16x32_bf16(
                        af[mt][s], bfr[ntx][s], acc[mt][ntx], 0, 0, 0);
        if (t + 1 < nt_) commit(buf ^ 1);         // write-late
        __syncthreads();
    }

#pragma unroll
    for (int mt = 0; mt < 4; mt++) {
#pragma unroll
        for (int r = 0; r < 4; r++) {
            int m = m0 + wm * 64 + mt * 16 + quad * 4 + r;
            if (m >= cnt) continue;
            if (W1OUT) {
                size_t ci = (size_t)(row0 + m);
#pragma unroll
                for (int ntx = 0; ntx < 2; ntx++) {
                    int col = n0 + wn * 32 + ntx * 16 + l15;
                    float v = acc[mt][ntx][r] + bias[e * N + col];
                    Cb[ci * N + col] = (__bf16)fmaxf(v, 0.f);
                }
            } else {
                int tok = sorted[row0 + m];
                float sc = scale[tok];
#pragma unroll
                for (int ntx = 0; ntx < 2; ntx++) {
                    int col = n0 + wn * 32 + ntx * 16 + l15;
                    Cf[(size_t)tok * N + col] = acc[mt][ntx][r] * sc;
                }
            }
        }
    }
}

// ---------------------------------------------------------------- MFMA GEMM (dense, f32 in)
#define MBM 128
#define MBN 64
#define MBK 32
#define LDAS 40

template<bool RELU, bool BIAS>
__global__ __launch_bounds__(256) void mgemm_k(
    const float* __restrict__ A, int lda,
    const float* __restrict__ Bw, const float* __restrict__ bias,
    float* __restrict__ C, int ldc, int M, int N, int K, int remM)
{
    __shared__ __align__(16) __bf16 As[MBM * LDAS];
    __shared__ __align__(16) __bf16 Bs[MBN * LDAS];

    int m0 = blockIdx.y * MBM;
    int n0 = blockIdx.x * MBN;

    int tid = threadIdx.x;
    int arow = tid >> 1, ahalf = tid & 1;
    const float* aptr = A + (size_t)(m0 + arow) * lda + ahalf * 16;
    int asw = (arow >> 3) & 3;
    int bn = tid & 63, bkc = tid >> 6;
    int bcs = bkc ^ ((bn >> 3) & 3);

    int lane = tid & 63, wid = tid >> 6;
    int wm = wid & 1, wn = wid >> 1;
    int l15 = lane & 15, quad = lane >> 4;

    int aoff[4], boff[2];
#pragma unroll
    for (int mt = 0; mt < 4; mt++) {
        int m = wm * 64 + mt * 16 + l15;
        aoff[mt] = m * LDAS + (quad ^ ((m >> 3) & 3)) * 8;
    }
#pragma unroll
    for (int nt = 0; nt < 2; nt++) {
        int n = wn * 32 + nt * 16 + l15;
        boff[nt] = n * LDAS + (quad ^ ((n >> 3) & 3)) * 8;
    }

    f32x4 acc[4][2];
#pragma unroll
    for (int mt = 0; mt < 4; mt++)
#pragma unroll
        for (int nt = 0; nt < 2; nt++)
#pragma unroll
            for (int r = 0; r < 4; r++) acc[mt][nt][r] = 0.f;

    for (int k0 = 0; k0 < K; k0 += MBK) {
#pragma unroll
        for (int cc = 0; cc < 2; cc++) {
            float4 f0 = *(const float4*)(aptr + k0 + cc * 8);
            float4 f1 = *(const float4*)(aptr + k0 + cc * 8 + 4);
            uint4 pk = make_uint4(pk2(f0.x, f0.y), pk2(f0.z, f0.w),
                                  pk2(f1.x, f1.y), pk2(f1.z, f1.w));
            int cs = (ahalf * 2 + cc) ^ asw;
            *(uint4*)&As[arow * LDAS + cs * 8] = pk;
        }
        {
            float f[8];
            int kk = k0 + bkc * 8;
#pragma unroll
            for (int i = 0; i < 8; i++)
                f[i] = Bw[(size_t)(kk + i) * N + n0 + bn];
            uint4 pk = make_uint4(pk2(f[0], f[1]), pk2(f[2], f[3]),
                                  pk2(f[4], f[5]), pk2(f[6], f[7]));
            *(uint4*)&Bs[bn * LDAS + bcs * 8] = pk;
        }
        __syncthreads();
        bf16x8 af[4], bfm[2];
#pragma unroll
        for (int mt = 0; mt < 4; mt++) af[mt] = *(const bf16x8*)&As[aoff[mt]];
#pragma unroll
        for (int nt = 0; nt < 2; nt++) bfm[nt] = *(const bf16x8*)&Bs[boff[nt]];
#pragma unroll
        for (int mt = 0; mt < 4; mt++)
#pragma unroll
            for (int nt = 0; nt < 2; nt++)
                acc[mt][nt] = __builtin_amdgcn_mfma_f32_16x16x32_bf16(
                    af[mt], bfm[nt], acc[mt][nt], 0, 0, 0);
        __syncthreads();
    }

#pragma unroll
    for (int mt = 0; mt < 4; mt++) {
#pragma unroll
        for (int r = 0; r < 4; r++) {
            int mi = wm * 64 + mt * 16 + quad * 4 + r;
            int m = m0 + mi;
            size_t crow = (size_t)m;
            if (remM) crow = (size_t)m + (size_t)(m >> 9) * remM;
#pragma unroll
            for (int nt = 0; nt < 2; nt++) {
                int col = n0 + wn * 32 + nt * 16 + l15;
                float v = acc[mt][nt][r];
                if (BIAS) v += bias[col];
                if (RELU) v = fmaxf(v, 0.f);
                C[crow * (size_t)ldc + col] = v;
            }
        }
    }
}

// ---------------------------------------------------------------- fused QKV MFMA GEMM
__global__ __launch_bounds__(256) void qkv_k(
    const float* __restrict__ A,          // [BT_][512]
    const float* __restrict__ wq, const float* __restrict__ wk,
    const float* __restrict__ wv,
    float* __restrict__ qo, float* __restrict__ ko, float* __restrict__ vo)
{
    __shared__ __align__(16) __bf16 As[MBM * LDAS];
    __shared__ __align__(16) __bf16 Bs[MBN * LDAS];

    int n0g = blockIdx.x * MBN;
    int which = n0g >> 9;
    int n0 = n0g & 511;
    const float* Bp = (which == 0) ? wq : (which == 1) ? wk : wv;
    float* Cp = (which == 0) ? qo : (which == 1) ? ko : vo;
    int m0 = blockIdx.y * MBM;

    int tid = threadIdx.x;
    int arow = tid >> 1, ahalf = tid & 1;
    const float* aptr = A + (size_t)(m0 + arow) * D_ + ahalf * 16;
    int asw = (arow >> 3) & 3;
    int bn = tid & 63, bkc = tid >> 6;
    int bcs = bkc ^ ((bn >> 3) & 3);

    int lane = tid & 63, wid = tid >> 6;
    int wm = wid & 1, wn = wid >> 1;
    int l15 = lane & 15, quad = lane >> 4;

    int aoff[4], boff[2];
#pragma unroll
    for (int mt = 0; mt < 4; mt++) {
        int m = wm * 64 + mt * 16 + l15;
        aoff[mt] = m * LDAS + (quad ^ ((m >> 3) & 3)) * 8;
    }
#pragma unroll
    for (int nt = 0; nt < 2; nt++) {
        int n = wn * 32 + nt * 16 + l15;
        boff[nt] = n * LDAS + (quad ^ ((n >> 3) & 3)) * 8;
    }

    f32x4 acc[4][2];
#pragma unroll
    for (int mt = 0; mt < 4; mt++)
#pragma unroll
        for (int nt = 0; nt < 2; nt++)
#pragma unroll
            for (int r = 0; r < 4; r++) acc[mt][nt][r] = 0.f;

    for (int k0 = 0; k0 < D_; k0 += MBK) {
#pragma unroll
        for (int cc = 0; cc < 2; cc++) {
            float4 f0 = *(const float4*)(aptr + k0 + cc * 8);
            float4 f1 = *(const float4*)(aptr + k0 + cc * 8 + 4);
            uint4 pk = make_uint4(pk2(f0.x, f0.y), pk2(f0.z, f0.w),
                                  pk2(f1.x, f1.y), pk2(f1.z, f1.w));
            int cs = (ahalf * 2 + cc) ^ asw;
            *(uint4*)&As[arow * LDAS + cs * 8] = pk;
        }
        {
            float f[8];
            int kk = k0 + bkc * 8;
#pragma unroll
            for (int i = 0; i < 8; i++)
                f[i] = Bp[(size_t)(kk + i) * D_ + n0 + bn];
            uint4 pk = make_uint4(pk2(f[0], f[1]), pk2(f[2], f[3]),
                                  pk2(f[4], f[5]), pk2(f[6], f[7]));
            *(uint4*)&Bs[bn * LDAS + bcs * 8] = pk;
        }
        __syncthreads();
        bf16x8 af[4], bfm[2];
#pragma unroll
        for (int mt = 0; mt < 4; mt++) af[mt] = *(const bf16x8*)&As[aoff[mt]];
#pragma unroll
        for (int nt = 0; nt < 2; nt++) bfm[nt] = *(const bf16x8*)&Bs[boff[nt]];
#pragma unroll
        for (int mt = 0; mt < 4; mt++)
#pragma unroll
            for (int nt = 0; nt < 2; nt++)
                acc[mt][nt] = __builtin_amdgcn_mfma_f32_16x16x32_bf16(
                    af[mt], bfm[nt], acc[mt][nt], 0, 0, 0);
        __syncthreads();
    }

#pragma unroll
    for (int mt = 0; mt < 4; mt++) {
#pragma unroll
        for (int r = 0; r < 4; r++) {
            int mi = wm * 64 + mt * 16 + quad * 4 + r;
            int m = m0 + mi;
            size_t crow = which ? (size_t)(m + (m >> 9) * M_) : (size_t)m;
#pragma unroll
            for (int nt = 0; nt < 2; nt++) {
                int col = n0 + wn * 32 + nt * 16 + l15;
                Cp[crow * (size_t)D_ + col] = acc[mt][nt][r];
            }
        }
    }
}

// ---------------------------------------------------------------- small ops
__global__ void bucketall_k(const int* __restrict__ eidA, int* __restrict__ sortedA,
                            int* __restrict__ segA)
{
    __shared__ int cnt[E_]; __shared__ int cur[E_];
    int l = blockIdx.x;
    const int* eid = eidA + l * BT_;
    int* sorted = sortedA + l * BT_;
    int* seg = segA + l * 8;
    int tid = threadIdx.x;
    if (tid < E_) cnt[tid] = 0;
    __syncthreads();
    for (int t = tid; t < BT_; t += 256) atomicAdd(&cnt[eid[t]], 1);
    __syncthreads();
    if (tid == 0) {
        int o = 0;
        for (int e = 0; e < E_; e++) { seg[e] = o; cur[e] = o; o += cnt[e]; }
        seg[E_] = o;
    }
    __syncthreads();
    for (int t = tid; t < BT_; t += 256) {
        int pos = atomicAdd(&cur[eid[t]], 1);
        sorted[pos] = t;
    }
}

__global__ void fsmn_k(const float* __restrict__ p, const float* __restrict__ fb,
                       const float* __restrict__ fa, float* __restrict__ cur, int skip)
{
    int idx = blockIdx.x * 256 + threadIdx.x;
    int d = idx & 511;
    int t = (idx >> 9) & 511;
    float m = p[idx];
#pragma unroll
    for (int k = 0; k < 4; k++) {
        int tt = t - 2 * (k + 1);
        if (tt >= 0) m += fb[k * D_ + d] * p[idx - D_ * 2 * (k + 1)];
    }
    if (t + 1 < T_) m += fa[d] * p[idx + D_];
    if (skip) m += cur[idx];
    cur[idx] = m;
}

__global__ void addpe_k(float* __restrict__ cur) {
    int idx = blockIdx.x * 256 + threadIdx.x;
    int d = idx & 511, t = (idx >> 9) & 511;
    float div = expf((float)(d & ~1) * (-9.210340371976184f / (float)D_));
    float ang = (float)t * div;
    cur[idx] += (d & 1) ? cosf(ang) : sinf(ang);
}

__global__ void fillmem_k(const float* __restrict__ mk, const float* __restrict__ mv,
                          float* __restrict__ kbuf, float* __restrict__ vbuf)
{
    int idx = blockIdx.x * 256 + threadIdx.x;
    int d = idx & 511, m = (idx >> 9) & 63, b = idx >> 15;
    size_t row = (size_t)b * TKV_ + T_ + m;
    kbuf[row * D_ + d] = mk[m * D_ + d];
    vbuf[row * D_ + d] = mv[m * D_ + d];
}

// attention: one block = (b, h, 16 q rows); 4 rows per wave
#define QR 16
__global__ __launch_bounds__(256) void attn_k(
    const float* __restrict__ q, const float* __restrict__ kbuf,
    const float* __restrict__ vbuf, const int* __restrict__ seq_len,
    float* __restrict__ attno)
{
    __shared__ float kv[64 * 69];
    __shared__ float qs[QR][64];
    __shared__ float sc[QR][TKV_];
    int b = blockIdx.z, h = blockIdx.y, t0 = blockIdx.x * QR;
    int tid = threadIdx.x, w = tid >> 6, lane = tid & 63;
    int r0 = w * 4;
#pragma unroll
    for (int i = 0; i < 4; i++) {
        int idx = tid + 256 * i;
        int r = idx >> 6, d = idx & 63;
        qs[r][d] = q[((size_t)(b * T_) + t0 + r) * D_ + h * DH_ + d] * 0.125f;
    }
    int sl = seq_len[b];
    for (int s0 = 0; s0 < TKV_; s0 += 64) {
        __syncthreads();
#pragma unroll
        for (int i = 0; i < 16; i++) {
            int idx = tid + 256 * i;
            int key = idx >> 6, d = idx & 63;
            kv[d * 69 + key] = kbuf[((size_t)b * TKV_ + s0 + key) * D_ + h * DH_ + d];
        }
        __syncthreads();
        float a0 = 0, a1 = 0, a2 = 0, a3 = 0;
#pragma unroll 4
        for (int d = 0; d < 64; d++) {
            float kvv = kv[d * 69 + lane];
            a0 += qs[r0 + 0][d] * kvv;
            a1 += qs[r0 + 1][d] * kvv;
            a2 += qs[r0 + 2][d] * kvv;
            a3 += qs[r0 + 3][d] * kvv;
        }
        int sa = s0 + lane;
        bool ok = (sa >= T_ || sa < sl);
        sc[r0 + 0][sa] = ok ? a0 : -1e9f;
        sc[r0 + 1][sa] = ok ? a1 : -1e9f;
        sc[r0 + 2][sa] = ok ? a2 : -1e9f;
        sc[r0 + 3][sa] = ok ? a3 : -1e9f;
    }
    float inv[4];
#pragma unroll
    for (int r = 0; r < 4; r++) {
        float mx = -1e30f;
        for (int s = lane; s < TKV_; s += 64) mx = fmaxf(mx, sc[r0 + r][s]);
        for (int off = 32; off; off >>= 1) mx = fmaxf(mx, __shfl_xor(mx, off));
        float sum = 0.f;
        for (int s = lane; s < TKV_; s += 64) {
            float e2 = expf(sc[r0 + r][s] - mx); sc[r0 + r][s] = e2; sum += e2;
        }
        for (int off = 32; off; off >>= 1) sum += __shfl_xor(sum, off);
        inv[r] = 1.f / sum;
    }
    float o0 = 0, o1 = 0, o2 = 0, o3 = 0;
    for (int s0 = 0; s0 < TKV_; s0 += 64) {
        __syncthreads();
#pragma unroll
        for (int i = 0; i < 16; i++) {
            int idx = tid + 256 * i;
            int key = idx >> 6, d = idx & 63;
            kv[key * 69 + d] = vbuf[((size_t)b * TKV_ + s0 + key) * D_ + h * DH_ + d];
        }
        __syncthreads();
#pragma unroll 4
        for (int j = 0; j < 64; j++) {
            float vv = kv[j * 69 + lane];
            o0 += sc[r0 + 0][s0 + j] * vv;
            o1 += sc[r0 + 1][s0 + j] * vv;
            o2 += sc[r0 + 2][s0 + j] * vv;
            o3 += sc[r0 + 3][s0 + j] * vv;
        }
    }
    size_t base = ((size_t)(b * T_) + t0 + r0) * D_ + h * DH_ + lane;
    attno[base + 0 * D_] = o0 * inv[0];
    attno[base + 1 * D_] = o1 * inv[1];
    attno[base + 2 * D_] = o2 * inv[2];
    attno[base + 3 * D_] = o3 * inv[3];
}

__global__ void ln_k(const float* __restrict__ o, const float* __restrict__ g,
                     const float* __restrict__ bb, float* __restrict__ cur)
{
    int w = threadIdx.x >> 6, lane = threadIdx.x & 63;
    size_t row = (size_t)(blockIdx.x * 4 + w);
    float v[8]; float s = 0.f;
#pragma unroll
    for (int i = 0; i < 8; i++) {
        int d = lane + 64 * i;
        v[i] = cur[row * D_ + d] + o[row * D_ + d];
        s += v[i];
    }
    for (int off = 32; off; off >>= 1) s += __shfl_xor(s, off);
    float mu = s * (1.f / D_);
    float vs = 0.f;
#pragma unroll
    for (int i = 0; i < 8; i++) { float dd = v[i] - mu; vs += dd * dd; }
    for (int off = 32; off; off >>= 1) vs += __shfl_xor(vs, off);
    float rstd = rsqrtf(vs * (1.f / D_) + 1e-5f);
#pragma unroll
    for (int i = 0; i < 8; i++) {
        int d = lane + 64 * i;
        cur[row * D_ + d] = (v[i] - mu) * rstd * g[d] + bb[d];
    }
}

// reduce impPart[RBLK_][32] -> imp[8][4], then cv^2 sum (deterministic)
__global__ __launch_bounds__(256) void aux_k(const float* __restrict__ impPart,
                                             float* __restrict__ outp)
{
    __shared__ float red[8][32];
    __shared__ float imp[32];
    int tid = threadIdx.x;
    int c = tid & 31, p = tid >> 5;
    float s = 0.f;
    for (int b = p; b < RBLK_; b += 8) s += impPart[(size_t)b * 32 + c];
    red[p][c] = s;
    __syncthreads();
    if (tid < 32) {
        float t = 0.f;
#pragma unroll
        for (int i = 0; i < 8; i++) t += red[i][tid];
        imp[tid] = t;
    }
    __syncthreads();
    if (tid == 0) {
        float total = 0.f;
        for (int l = 0; l < 8; l++) {
            const float* ip = imp + l * 4;
            float m = (ip[0] + ip[1] + ip[2] + ip[3]) * 0.25f;
            float var = 0.f;
            for (int e = 0; e < 4; e++) { float d = ip[e] - m; var += d * d; }
            var *= 0.25f;
            total += var / (m * m + 1e-9f);
        }
        *outp = total;
    }
}

// ============================================================================
extern "C" void kernel_launch(void* const* d_in, const int* in_sizes, int n_in,
                              void* d_out, int out_size, void* d_ws, size_t ws_size,
                              hipStream_t stream)
{
    (void)in_sizes; (void)n_in; (void)out_size; (void)ws_size;
    const float* x        = (const float*)d_in[0];
    const int*   seqlen   = (const int*)d_in[1];
    const float* emb_w1   = (const float*)d_in[2];
    const float* emb_b1   = (const float*)d_in[3];
    const float* emb_w2   = (const float*)d_in[4];
    const float* emb_wo   = (const float*)d_in[5];
    const float* f0_w1    = (const float*)d_in[6];
    const float* f0_b1    = (const float*)d_in[7];
    const float* f0_w2    = (const float*)d_in[8];
    const float* f0_router= (const float*)d_in[9];
    const float* f0_fb    = (const float*)d_in[10];
    const float* f0_fa    = (const float*)d_in[11];
    const float* f_w1     = (const float*)d_in[12];
    const float* f_b1     = (const float*)d_in[13];
    const float* f_w2     = (const float*)d_in[14];
    const float* f_router = (const float*)d_in[15];
    const float* f_fb     = (const float*)d_in[16];
    const float* f_fa     = (const float*)d_in[17];
    const float* attn_wq  = (const float*)d_in[18];
    const float* attn_wk  = (const float*)d_in[19];
    const float* attn_wv  = (const float*)d_in[20];
    const float* attn_wo  = (const float*)d_in[21];
    const float* attn_mk  = (const float*)d_in[22];
    const float* attn_mv  = (const float*)d_in[23];
    const float* ln_g     = (const float*)d_in[24];
    const float* ln_b     = (const float*)d_in[25];
    const float* out_w    = (const float*)d_in[26];
    const float* out_b    = (const float*)d_in[27];

    float* out0 = (float*)d_out;
    float* out1 = out0 + (size_t)BT_ * OUT_;
    float* out2 = out1 + (size_t)BT_ * OUT_;

    float* fws = (float*)d_ws;
    size_t o = 0;
    float* embedF = fws + o; o += (size_t)BT_ * D_;       // 1M floats
    float* curB   = fws + o; o += (size_t)BT_ * D_;       // 1M
    float* hbuf   = fws + o; o += (size_t)BT_ * HID_;     // 2M (h | Ag+hbufh | attno+tmpo)
    float* pbuf   = fws + o; o += (size_t)BT_ * D_;       // 1M
    float* kbuf   = fws + o; o += (size_t)B_ * TKV_ * D_; // 1.125M (also w1h)
    float* vbuf   = fws + o; o += (size_t)B_ * TKV_ * D_; // 1.125M (also w2h)
    float* gatev  = fws + o; o += (size_t)8 * BT_;
    float* impPart= fws + o; o += (size_t)RBLK_ * 32;
    float* R2     = fws + o; o += (size_t)8 * 1024 * 4;
    int* eid     = (int*)(fws + o); o += (size_t)8 * BT_;
    int* sortedA = (int*)(fws + o); o += (size_t)8 * BT_;
    int* segA    = (int*)(fws + o); o += 64;
    // ---- aliases (lifetimes disjoint; total ws = round-5's proven 34.8 MB)
    __bf16* Ag    = (__bf16*)hbuf;                        // [2048][<=512] bf16 (0.5M fl)
    __bf16* hbufh = (__bf16*)(hbuf + (size_t)BT_ * D_ / 2); // [2048][1024] bf16 (1M fl)
    __bf16* w1h   = (__bf16*)kbuf;                        // [4][Kpad][1024] bf16 (<=1M fl)
    __bf16* w2h   = (__bf16*)vbuf;                        // [4][1024][512] bf16 (1M fl)
    float* qbuf  = pbuf;
    float* attno = hbuf;                                  // [2048][512]
    float* tmpo  = hbuf + (size_t)BT_ * D_;               // [2048][512]

    // h = relu(x@emb_w1+b1) — exact f32 (feeds routing), fast K=80 kernel
    gemm80_k<<<dim3(HID_ / 64, BT_ / 64, 1), 256, 0, stream>>>(x, emb_w1, emb_b1, hbuf);
    // R2[l] = emb_w2 @ router_l in f64 — routing reassociation adds ~0 error
    wr2_k<<<256, 256, 0, stream>>>(emb_w2, f0_router, f_router, R2);
    // all 8 layers' routing decisions in one pass over h (no global atomics)
    routerall_k<<<RBLK_, 256, 0, stream>>>(hbuf, R2, seqlen, eid, gatev, impPart);
    // all 8 bucket sorts, one dispatch
    bucketall_k<<<8, 256, 0, stream>>>(eid, sortedA, segA);
    // embedF only feeds embed_out -> bf16 MFMA is fine
    mgemm_k<false,false><<<dim3(D_/MBN, BT_/MBM, 1), 256, 0, stream>>>(
        hbuf, HID_, emb_w2, nullptr, embedF, D_, BT_, D_, HID_, 0);
    mgemm_k<false,false><<<dim3(OUT_/MBN, BT_/MBM, 1), 256, 0, stream>>>(
        embedF, D_, emb_wo, nullptr, out1, OUT_, BT_, OUT_, D_, 0);
    // NOTE: hbuf (h) is dead from here on -> Ag/hbufh may reuse it.

    for (int l = 0; l < 8; l++) {
        const float* w1  = (l == 0) ? f0_w1 : f_w1 + (size_t)(l-1) * E_ * D_ * HID_;
        const float* b1p = (l == 0) ? f0_b1 : f_b1 + (size_t)(l-1) * E_ * HID_;
        const float* w2  = (l == 0) ? f0_w2 : f_w2 + (size_t)(l-1) * E_ * HID_ * D_;
        const float* fbp = (l == 0) ? f0_fb : f_fb + (size_t)(l-1) * 4 * D_;
        const float* fap = (l == 0) ? f0_fa : f_fa + (size_t)(l-1) * 1 * D_;
        const float* Ain = (l == 0) ? x : curB;
        int lda  = (l == 0) ? IN_ : D_;
        int Ks   = (l == 0) ? IN_ : D_;     // true K
        int Kp   = (l == 0) ? 128 : 512;    // padded K (MBK=64 granular)
        int kpsh = (l == 0) ? 7 : 9;
        const int* seg = segA + l * 8;
        const int* sorted = sortedA + l * BT_;

        // per-layer bf16 weight conversion (into kbuf/vbuf regions)
        cvtw_k<<<E_ * Kp * HID_ / 8 / 256, 256, 0, stream>>>(w1, w1h, 10, kpsh, Ks);
        cvtw_k<<<E_ * HID_ * D_ / 8 / 256, 256, 0, stream>>>(w2, w2h, 9, 10, HID_);
        // A rows gathered to sorted order, bf16, K zero-padded
        gathera_k<<<BT_ * Kp / 8 / 256, 256, 0, stream>>>(Ain, lda, sorted, Ag, kpsh, Ks);

        egemm_k<true><<<dim3(HID_/64, BT_/128, E_), 256, 0, stream>>>(
            Ag, w1h, b1p, hbufh, nullptr, HID_, Kp, seg, nullptr, nullptr);
        egemm_k<false><<<dim3(D_/64, BT_/128, E_), 256, 0, stream>>>(
            hbufh, w2h, nullptr, nullptr, pbuf, D_, HID_, seg, sorted, gatev + l * BT_);
        fsmn_k<<<BT_*D_/256, 256, 0, stream>>>(pbuf, fbp, fap, curB, (l > 0) ? 1 : 0);

        if (l == 3) addpe_k<<<BT_*D_/256, 256, 0, stream>>>(curB);

        if (l == 3 || l == 7) {
            int ab = (l == 3) ? 0 : 1;
            const float* wq = attn_wq + (size_t)ab * D_ * D_;
            const float* wk = attn_wk + (size_t)ab * D_ * D_;
            const float* wv = attn_wv + (size_t)ab * D_ * D_;
            const float* wo = attn_wo + (size_t)ab * D_ * D_;
            const float* mk = attn_mk + (size_t)ab * M_ * D_;
            const float* mv = attn_mv + (size_t)ab * M_ * D_;
            const float* g  = ln_g + (size_t)ab * D_;
            const float* bb = ln_b + (size_t)ab * D_;

            // kbuf/vbuf (w1h/w2h) are dead now; qkv overwrites them.
            qkv_k<<<dim3(3 * D_ / MBN, BT_ / MBM, 1), 256, 0, stream>>>(
                curB, wq, wk, wv, qbuf, kbuf, vbuf);
            fillmem_k<<<B_*M_*D_/256, 256, 0, stream>>>(mk, mv, kbuf, vbuf);
            attn_k<<<dim3(T_/QR, H_, B_), 256, 0, stream>>>(qbuf, kbuf, vbuf, seqlen, attno);
            mgemm_k<false,false><<<dim3(D_/MBN, BT_/MBM, 1), 256, 0, stream>>>(
                attno, D_, wo, nullptr, tmpo, D_, BT_, D_, D_, 0);
            ln_k<<<BT_/4, 256, 0, stream>>>(tmpo, g, bb, curB);
        }
    }

    mgemm_k<false,true><<<dim3(OUT_/MBN, BT_/MBM, 1), 256, 0, stream>>>(
        curB, D_, out_w, out_b, out0, OUT_, BT_, OUT_, D_, 0);
    aux_k<<<1, 256, 0, stream>>>(impPart, out2);
}